// Round 1
// baseline (1547.064 us; speedup 1.0000x reference)
//
#include <hip/hip_runtime.h>
#include <hip/hip_bf16.h>
#include <math.h>

#define H 128

// ---------------- CSR construction ----------------

__global__ void count_deg_kernel(const int* __restrict__ dst, int* __restrict__ deg, int e) {
    int i = blockIdx.x * 256 + threadIdx.x;
    if (i < e) atomicAdd(&deg[dst[i]], 1);
}

__global__ void scan_block_kernel(const int* __restrict__ deg, int* __restrict__ rs,
                                  int* __restrict__ bsums, int n) {
    __shared__ int wsum[16];
    int i = blockIdx.x * 1024 + threadIdx.x;
    int v = (i < n) ? deg[i] : 0;
    int lane = threadIdx.x & 63;
    int wid = threadIdx.x >> 6;
    int x = v;
    #pragma unroll
    for (int off = 1; off < 64; off <<= 1) {
        int y = __shfl_up(x, off, 64);
        if (lane >= off) x += y;
    }
    if (lane == 63) wsum[wid] = x;
    __syncthreads();
    if (threadIdx.x == 0) {
        int acc = 0;
        #pragma unroll
        for (int w = 0; w < 16; w++) { int t = wsum[w]; wsum[w] = acc; acc += t; }
        bsums[blockIdx.x] = acc;
    }
    __syncthreads();
    int excl = x - v + wsum[wid];
    if (i < n) rs[i] = excl;
}

__global__ void scan_sums_kernel(int* __restrict__ bsums, int nb, int* __restrict__ rs, int n, int e) {
    if (threadIdx.x == 0 && blockIdx.x == 0) {
        int acc = 0;
        for (int i = 0; i < nb; i++) { int t = bsums[i]; bsums[i] = acc; acc += t; }
        rs[n] = e;
    }
}

__global__ void add_offsets_kernel(int* __restrict__ rs, const int* __restrict__ bsums, int n) {
    int i = blockIdx.x * 1024 + threadIdx.x;
    if (i < n) rs[i] += bsums[blockIdx.x];
}

__global__ void fill_csr_kernel(const int* __restrict__ src, const int* __restrict__ dst,
                                const int* __restrict__ rs, int* __restrict__ cursor,
                                int* __restrict__ csr, int e) {
    int i = blockIdx.x * 256 + threadIdx.x;
    if (i < e) {
        int d = dst[i];
        int pos = rs[d] + atomicAdd(&cursor[d], 1);
        csr[pos] = src[i];
    }
}

// ---------------- Layer 0 (in_dim = 1) ----------------

__global__ void agg0_kernel(const float* __restrict__ x, const int* __restrict__ rs,
                            const int* __restrict__ csr, const int* __restrict__ deg,
                            float* __restrict__ agg0, int n) {
    int i = blockIdx.x * 256 + threadIdx.x;
    if (i >= n) return;
    int a = rs[i], b = rs[i + 1];
    float s = 0.f;
    for (int e = a; e < b; e++) s += x[csr[e]];
    agg0[i] = s / (float)max(deg[i], 1);
}

__global__ void expand0_kernel(const float* __restrict__ x, const float* __restrict__ agg0,
                               const float* __restrict__ Wl0, const float* __restrict__ bl0,
                               const float* __restrict__ Wr0, float* __restrict__ hout, int n) {
    int idx = blockIdx.x * 256 + threadIdx.x;
    if (idx >= n * H) return;
    int i = idx >> 7, j = idx & (H - 1);
    float v = agg0[i] * Wl0[j] + bl0[j] + x[i] * Wr0[j];
    hout[idx] = fmaxf(v, 0.f);
}

// ---------------- Aggregate (scatter-mean via CSR gather) ----------------

__global__ void aggregate_kernel(const float* __restrict__ hin, const int* __restrict__ rs,
                                 const int* __restrict__ csr, const int* __restrict__ deg,
                                 float* __restrict__ agg, int n) {
    __shared__ int nbr[H];
    int i = blockIdx.x;
    int f = threadIdx.x;
    int a = rs[i], b = rs[i + 1];
    float acc = 0.f;
    for (int base = a; base < b; base += H) {
        int m = min(b - base, H);
        if (f < m) nbr[f] = csr[base + f];
        __syncthreads();
        for (int e = 0; e < m; e++) acc += hin[(size_t)nbr[e] * H + f];
        __syncthreads();
    }
    agg[(size_t)i * H + f] = acc / (float)max(deg[i], 1);
}

// ---------------- Dense: out = relu(agg@Wl + bl + h@Wr), in-place safe into agg ----------------

__global__ __launch_bounds__(128, 1) void matmul_relu_kernel(
    const float* __restrict__ aggp, const float* __restrict__ hp,
    const float* __restrict__ Wl, const float* __restrict__ Wr,
    const float* __restrict__ bl, float* __restrict__ out, int n) {
    int j = threadIdx.x;
    float wl[H], wr[H];
    #pragma unroll
    for (int k = 0; k < H; k++) { wl[k] = Wl[k * H + j]; wr[k] = Wr[k * H + j]; }
    float bj = bl[j];
    for (int r = blockIdx.x; r < n; r += gridDim.x) {
        const float* ar = aggp + (size_t)r * H;
        const float* hr = hp + (size_t)r * H;
        float a0 = 0.f, a1 = 0.f, a2 = 0.f, a3 = 0.f;
        #pragma unroll
        for (int k = 0; k < H; k += 4) {
            a0 += ar[k] * wl[k];
            a1 += ar[k + 1] * wl[k + 1];
            a2 += ar[k + 2] * wl[k + 2];
            a3 += ar[k + 3] * wl[k + 3];
        }
        #pragma unroll
        for (int k = 0; k < H; k += 4) {
            a0 += hr[k] * wr[k];
            a1 += hr[k + 1] * wr[k + 1];
            a2 += hr[k + 2] * wr[k + 2];
            a3 += hr[k + 3] * wr[k + 3];
        }
        float acc = bj + (a0 + a1) + (a2 + a3);
        __syncthreads();  // both waves done reading row r before overwriting (out may alias aggp)
        out[(size_t)r * H + j] = fmaxf(acc, 0.f);
    }
}

// ---------------- Pooling (fixed-order, deterministic) ----------------

__global__ void pool_partial_kernel(const float* __restrict__ h, float* __restrict__ partial, int n) {
    int f = threadIdx.x;
    int b = blockIdx.x;
    float s = 0.f;
    for (int r = b; r < n; r += gridDim.x) s += h[(size_t)r * H + f];
    partial[b * H + f] = s;
}

__global__ void pool_final_kernel(const float* __restrict__ partial, float* __restrict__ pooled,
                                  int nb, float invn) {
    int f = threadIdx.x;
    float s = 0.f;
    for (int b = 0; b < nb; b++) s += partial[b * H + f];
    pooled[f] = s * invn;
}

// ---------------- Final MLP ----------------

__global__ void mlp_kernel(const float* __restrict__ pooled,
                           const float* __restrict__ Wv, const float* __restrict__ bv,
                           const float* __restrict__ temp, const float* __restrict__ tt,
                           const float* __restrict__ Wm1, const float* __restrict__ bm1,
                           const float* __restrict__ Wm2, const float* __restrict__ bm2,
                           float* __restrict__ out) {
    __shared__ float feat[66];
    __shared__ float red[2];
    int j = threadIdx.x;  // 128 threads
    if (j < 64) {
        float s = bv[j];
        for (int k = 0; k < H; k++) s += pooled[k] * Wv[k * 64 + j];
        feat[j] = s;
    }
    if (j == 64) feat[64] = temp[0];
    if (j == 65) feat[65] = tt[0];
    __syncthreads();
    float m = bm1[j];
    for (int k = 0; k < 66; k++) m += feat[k] * Wm1[k * H + j];
    m = fmaxf(m, 0.f);
    float p = m * Wm2[j];
    #pragma unroll
    for (int off = 32; off > 0; off >>= 1) p += __shfl_down(p, off, 64);
    if ((j & 63) == 0) red[j >> 6] = p;
    __syncthreads();
    if (j == 0) {
        float x = red[0] + red[1] + bm2[0];
        out[0] = (x > 20.f) ? x : log1pf(expf(x));
    }
}

// ---------------- Launch ----------------

extern "C" void kernel_launch(void* const* d_in, const int* in_sizes, int n_in,
                              void* d_out, int out_size, void* d_ws, size_t ws_size,
                              hipStream_t stream) {
    const float* node_feats = (const float*)d_in[0];
    const int* edge_index = (const int*)d_in[1];
    const float* temp = (const float*)d_in[3];
    const float* tt   = (const float*)d_in[4];
    const float* Wl0 = (const float*)d_in[5];
    const float* bl0 = (const float*)d_in[6];
    const float* Wr0 = (const float*)d_in[7];
    const float* Wl  = (const float*)d_in[8];
    const float* bl  = (const float*)d_in[9];
    const float* Wr  = (const float*)d_in[10];
    const float* Wv  = (const float*)d_in[11];
    const float* bv  = (const float*)d_in[12];
    const float* Wm1 = (const float*)d_in[13];
    const float* bm1 = (const float*)d_in[14];
    const float* Wm2 = (const float*)d_in[15];
    const float* bm2 = (const float*)d_in[16];

    const int N = in_sizes[0];
    const int E = in_sizes[1] / 2;
    const int* src = edge_index;
    const int* dst = edge_index + E;

    size_t NH = (size_t)N * H;
    float* A = (float*)d_ws;              // h buffer
    float* B = A + NH;                    // agg / h buffer
    float* agg0 = B + NH;                 // N
    int* deg = (int*)(agg0 + N);          // N
    int* rs = deg + N;                    // N+1
    int* cursor = rs + (N + 1);           // N
    int* csr = cursor + N;                // E
    int* bsums = csr + E;                 // <=256
    float* partial = (float*)(bsums + 256);  // 256*H
    float* pooled = partial + 256 * H;    // H

    // CSR build
    hipMemsetAsync(deg, 0, (size_t)N * sizeof(int), stream);
    hipMemsetAsync(cursor, 0, (size_t)N * sizeof(int), stream);
    count_deg_kernel<<<(E + 255) / 256, 256, 0, stream>>>(dst, deg, E);
    int nb = (N + 1023) / 1024;
    scan_block_kernel<<<nb, 1024, 0, stream>>>(deg, rs, bsums, N);
    scan_sums_kernel<<<1, 64, 0, stream>>>(bsums, nb, rs, N, E);
    add_offsets_kernel<<<nb, 1024, 0, stream>>>(rs, bsums, N);
    fill_csr_kernel<<<(E + 255) / 256, 256, 0, stream>>>(src, dst, rs, cursor, csr, E);

    // Layer 0: 1 -> H
    agg0_kernel<<<(N + 255) / 256, 256, 0, stream>>>(node_feats, rs, csr, deg, agg0, N);
    expand0_kernel<<<((size_t)N * H + 255) / 256, 256, 0, stream>>>(node_feats, agg0, Wl0, bl0, Wr0, A, N);

    // Layer 1: h=A -> agg=B -> out=B
    aggregate_kernel<<<N, H, 0, stream>>>(A, rs, csr, deg, B, N);
    matmul_relu_kernel<<<1024, H, 0, stream>>>(B, A, Wl + 0 * H * H, Wr + 0 * H * H, bl + 0 * H, B, N);

    // Layer 2: h=B -> agg=A -> out=A
    aggregate_kernel<<<N, H, 0, stream>>>(B, rs, csr, deg, A, N);
    matmul_relu_kernel<<<1024, H, 0, stream>>>(A, B, Wl + 1 * H * H, Wr + 1 * H * H, bl + 1 * H, A, N);

    // Pool over nodes (h = A)
    pool_partial_kernel<<<256, H, 0, stream>>>(A, partial, N);
    pool_final_kernel<<<1, H, 0, stream>>>(partial, pooled, 256, 1.0f / (float)N);

    // Final MLP
    mlp_kernel<<<1, H, 0, stream>>>(pooled, Wv, bv, temp, tt, Wm1, bm1, Wm2, bm2, (float*)d_out);
}

// Round 2
// 632.306 us; speedup vs baseline: 2.4467x; 2.4467x over previous
//
#include <hip/hip_runtime.h>
#include <hip/hip_bf16.h>
#include <math.h>

#define H 128

typedef __attribute__((ext_vector_type(8))) short short8;
typedef __attribute__((ext_vector_type(4))) float f32x4;

static __device__ __forceinline__ ushort f2b(float v) {
    union { float f; unsigned u; } x; x.f = v;
    unsigned r = x.u + 0x7fffu + ((x.u >> 16) & 1u);
    return (ushort)(r >> 16);
}
static __device__ __forceinline__ float b2f(ushort b) {
    union { unsigned u; float f; } x; x.u = ((unsigned)b) << 16;
    return x.f;
}

// ---------------- CSR construction ----------------

__global__ void count_deg_kernel(const int* __restrict__ dst, int* __restrict__ deg, int e) {
    int i = blockIdx.x * 256 + threadIdx.x;
    if (i < e) atomicAdd(&deg[dst[i]], 1);
}

__global__ void scan_block_kernel(const int* __restrict__ deg, int* __restrict__ rs,
                                  int* __restrict__ bsums, int n) {
    __shared__ int wsum[16];
    int i = blockIdx.x * 1024 + threadIdx.x;
    int v = (i < n) ? deg[i] : 0;
    int lane = threadIdx.x & 63;
    int wid = threadIdx.x >> 6;
    int x = v;
    #pragma unroll
    for (int off = 1; off < 64; off <<= 1) {
        int y = __shfl_up(x, off, 64);
        if (lane >= off) x += y;
    }
    if (lane == 63) wsum[wid] = x;
    __syncthreads();
    if (threadIdx.x == 0) {
        int acc = 0;
        #pragma unroll
        for (int w = 0; w < 16; w++) { int t = wsum[w]; wsum[w] = acc; acc += t; }
        bsums[blockIdx.x] = acc;
    }
    __syncthreads();
    int excl = x - v + wsum[wid];
    if (i < n) rs[i] = excl;
}

__global__ void scan_sums_kernel(int* __restrict__ bsums, int nb, int* __restrict__ rs, int n, int e) {
    if (threadIdx.x == 0 && blockIdx.x == 0) {
        int acc = 0;
        for (int i = 0; i < nb; i++) { int t = bsums[i]; bsums[i] = acc; acc += t; }
        rs[n] = e;
    }
}

__global__ void add_offsets_kernel(int* __restrict__ rs, const int* __restrict__ bsums, int n) {
    int i = blockIdx.x * 1024 + threadIdx.x;
    if (i < n) rs[i] += bsums[blockIdx.x];
}

__global__ void fill_csr_kernel(const int* __restrict__ src, const int* __restrict__ dst,
                                const int* __restrict__ rs, int* __restrict__ cursor,
                                int* __restrict__ csr, int e) {
    int i = blockIdx.x * 256 + threadIdx.x;
    if (i < e) {
        int d = dst[i];
        int pos = rs[d] + atomicAdd(&cursor[d], 1);
        csr[pos] = src[i];
    }
}

// ---------------- Weight prep: Btg[layer][col][k] bf16, k<128 from Wl, k>=128 from Wr ----------------

__global__ void prep_w_kernel(const float* __restrict__ Wl, const float* __restrict__ Wr,
                              ushort* __restrict__ Btg) {
    int idx = blockIdx.x * 256 + threadIdx.x;   // 2*128*256 = 65536
    if (idx >= 65536) return;
    int l = idx >> 15;
    int col = (idx >> 8) & 127;
    int k = idx & 255;
    float v = (k < 128) ? Wl[l * H * H + k * H + col] : Wr[l * H * H + (k - 128) * H + col];
    Btg[idx] = f2b(v);
}

// ---------------- Layer 0 (in_dim = 1) ----------------

__global__ void agg0_kernel(const float* __restrict__ x, const int* __restrict__ rs,
                            const int* __restrict__ csr, const int* __restrict__ deg,
                            float* __restrict__ agg0, int n) {
    int i = blockIdx.x * 256 + threadIdx.x;
    if (i >= n) return;
    int a = rs[i], b = rs[i + 1];
    float s = 0.f;
    for (int e = a; e < b; e++) s += x[csr[e]];
    agg0[i] = s / (float)max(deg[i], 1);
}

__global__ void expand0_kernel(const float* __restrict__ x, const float* __restrict__ agg0,
                               const float* __restrict__ Wl0, const float* __restrict__ bl0,
                               const float* __restrict__ Wr0, ushort* __restrict__ hout, int n) {
    int idx = blockIdx.x * 256 + threadIdx.x;
    if (idx >= n * H) return;
    int i = idx >> 7, j = idx & (H - 1);
    float v = agg0[i] * Wl0[j] + bl0[j] + x[i] * Wr0[j];
    hout[idx] = f2b(fmaxf(v, 0.f));
}

// ---------------- Aggregate (CSR gather mean), bf16 in/out, f32 accumulate ----------------
// One wave per node; lane handles features [2l, 2l+1] (ushort2 -> 256B/wave coalesced).

__global__ void aggregate_kernel(const ushort* __restrict__ hb, const int* __restrict__ rs,
                                 const int* __restrict__ csr, const int* __restrict__ deg,
                                 ushort* __restrict__ aggb, int n) {
    int node = blockIdx.x * 4 + (threadIdx.x >> 6);
    int lane = threadIdx.x & 63;
    if (node >= n) return;
    int a = rs[node], b = rs[node + 1];
    float s0 = 0.f, s1 = 0.f;
    int e = a;
    for (; e + 4 <= b; e += 4) {
        int n0 = csr[e], n1 = csr[e + 1], n2 = csr[e + 2], n3 = csr[e + 3];
        ushort2 v0 = *(const ushort2*)(hb + (size_t)n0 * H + 2 * lane);
        ushort2 v1 = *(const ushort2*)(hb + (size_t)n1 * H + 2 * lane);
        ushort2 v2 = *(const ushort2*)(hb + (size_t)n2 * H + 2 * lane);
        ushort2 v3 = *(const ushort2*)(hb + (size_t)n3 * H + 2 * lane);
        s0 += b2f(v0.x) + b2f(v1.x) + b2f(v2.x) + b2f(v3.x);
        s1 += b2f(v0.y) + b2f(v1.y) + b2f(v2.y) + b2f(v3.y);
    }
    for (; e < b; e++) {
        int nb_ = csr[e];
        ushort2 v = *(const ushort2*)(hb + (size_t)nb_ * H + 2 * lane);
        s0 += b2f(v.x); s1 += b2f(v.y);
    }
    float inv = 1.f / (float)max(deg[node], 1);
    aggb[(size_t)node * H + 2 * lane]     = f2b(s0 * inv);
    aggb[(size_t)node * H + 2 * lane + 1] = f2b(s1 * inv);
}

// ---------------- Fused dual GEMM: out = relu([agg|h] @ [Wl;Wr] + b), bf16 MFMA ----------------
// M=n, N=128, K=256. Block = 4 waves; wave computes 16 rows x 128 cols.
// B (256x128) staged transposed+swizzled in LDS once per block; grid-stride over 64-row chunks.

__global__ __launch_bounds__(256, 2) void gemm_kernel(
    const ushort* __restrict__ aggb, const ushort* __restrict__ hb,
    const ushort* __restrict__ Btg,   // [128][256] bf16 for this layer
    const float* __restrict__ bias, ushort* __restrict__ out, int n) {
    __shared__ ushort Bt[128 * 256];  // 64 KB, [col][k] with kbyte ^= (col&7)<<4
    int tid = threadIdx.x;
    for (int c = tid; c < 4096; c += 256) {          // 4096 chunks of 16B
        int col = c >> 5;
        int kb = (c & 31) << 4;                       // byte offset along k
        short8 v = *(const short8*)(Btg + col * 256 + (kb >> 1));
        *(short8*)((char*)Bt + col * 512 + (kb ^ ((col & 7) << 4))) = v;
    }
    __syncthreads();

    int wave = tid >> 6, lane = tid & 63;
    int l15 = lane & 15;
    int lhi = lane >> 4;          // 0..3
    int klane = lhi * 8;          // element offset within 32-wide k-chunk

    for (int r0 = blockIdx.x * 64; r0 < n; r0 += gridDim.x * 64) {
        int row0 = r0 + wave * 16;
        int arow = row0 + l15;
        if (arow >= n) arow = n - 1;                  // clamp; store is masked

        f32x4 acc[8];
        #pragma unroll
        for (int c2 = 0; c2 < 8; c2++) acc[c2] = (f32x4){0.f, 0.f, 0.f, 0.f};

        #pragma unroll
        for (int s = 0; s < 8; s++) {
            const ushort* ap = (s < 4 ? aggb : hb) + (size_t)arow * H + (s & 3) * 32 + klane;
            short8 a = *(const short8*)ap;
            #pragma unroll
            for (int c2 = 0; c2 < 8; c2++) {
                int col = c2 * 16 + l15;
                int kb = s * 64 + lhi * 16;
                short8 b = *(const short8*)((char*)Bt + col * 512 + (kb ^ ((col & 7) << 4)));
                acc[c2] = __builtin_amdgcn_mfma_f32_16x16x32_bf16(a, b, acc[c2], 0, 0, 0);
            }
        }

        #pragma unroll
        for (int c2 = 0; c2 < 8; c2++) {
            int col = c2 * 16 + l15;
            float bj = bias[col];
            #pragma unroll
            for (int r = 0; r < 4; r++) {
                int row = row0 + lhi * 4 + r;
                if (row < n) out[(size_t)row * H + col] = f2b(fmaxf(acc[c2][r] + bj, 0.f));
            }
        }
    }
}

// ---------------- Pooling (fixed-order, deterministic) ----------------

__global__ void pool_partial_kernel(const ushort* __restrict__ h, float* __restrict__ partial, int n) {
    int w = blockIdx.x;            // 256 blocks of one wave
    int lane = threadIdx.x;        // 64
    float s0 = 0.f, s1 = 0.f;
    for (int r = w; r < n; r += 256) {
        ushort2 v = *(const ushort2*)(h + (size_t)r * H + 2 * lane);
        s0 += b2f(v.x); s1 += b2f(v.y);
    }
    partial[w * H + 2 * lane] = s0;
    partial[w * H + 2 * lane + 1] = s1;
}

__global__ void pool_final_kernel(const float* __restrict__ partial, float* __restrict__ pooled,
                                  int nb, float invn) {
    int f = threadIdx.x;
    float s = 0.f;
    for (int b = 0; b < nb; b++) s += partial[b * H + f];
    pooled[f] = s * invn;
}

// ---------------- Final MLP ----------------

__global__ void mlp_kernel(const float* __restrict__ pooled,
                           const float* __restrict__ Wv, const float* __restrict__ bv,
                           const float* __restrict__ temp, const float* __restrict__ tt,
                           const float* __restrict__ Wm1, const float* __restrict__ bm1,
                           const float* __restrict__ Wm2, const float* __restrict__ bm2,
                           float* __restrict__ out) {
    __shared__ float feat[66];
    __shared__ float red[2];
    int j = threadIdx.x;  // 128 threads
    if (j < 64) {
        float s = bv[j];
        for (int k = 0; k < H; k++) s += pooled[k] * Wv[k * 64 + j];
        feat[j] = s;
    }
    if (j == 64) feat[64] = temp[0];
    if (j == 65) feat[65] = tt[0];
    __syncthreads();
    float m = bm1[j];
    for (int k = 0; k < 66; k++) m += feat[k] * Wm1[k * H + j];
    m = fmaxf(m, 0.f);
    float p = m * Wm2[j];
    #pragma unroll
    for (int off = 32; off > 0; off >>= 1) p += __shfl_down(p, off, 64);
    if ((j & 63) == 0) red[j >> 6] = p;
    __syncthreads();
    if (j == 0) {
        float x = red[0] + red[1] + bm2[0];
        out[0] = (x > 20.f) ? x : log1pf(expf(x));
    }
}

// ---------------- Launch ----------------

extern "C" void kernel_launch(void* const* d_in, const int* in_sizes, int n_in,
                              void* d_out, int out_size, void* d_ws, size_t ws_size,
                              hipStream_t stream) {
    const float* node_feats = (const float*)d_in[0];
    const int* edge_index = (const int*)d_in[1];
    const float* temp = (const float*)d_in[3];
    const float* tt   = (const float*)d_in[4];
    const float* Wl0 = (const float*)d_in[5];
    const float* bl0 = (const float*)d_in[6];
    const float* Wr0 = (const float*)d_in[7];
    const float* Wl  = (const float*)d_in[8];
    const float* bl  = (const float*)d_in[9];
    const float* Wr  = (const float*)d_in[10];
    const float* Wv  = (const float*)d_in[11];
    const float* bv  = (const float*)d_in[12];
    const float* Wm1 = (const float*)d_in[13];
    const float* bm1 = (const float*)d_in[14];
    const float* Wm2 = (const float*)d_in[15];
    const float* bm2 = (const float*)d_in[16];

    const int N = in_sizes[0];
    const int E = in_sizes[1] / 2;
    const int* src = edge_index;
    const int* dst = edge_index + E;

    size_t NH = (size_t)N * H;
    ushort* hA   = (ushort*)d_ws;          // N*H bf16
    ushort* hB   = hA + NH;                // N*H bf16
    ushort* aggb = hB + NH;                // N*H bf16
    ushort* Btg  = aggb + NH;              // 2*128*256 bf16
    float* agg0  = (float*)(Btg + 65536);  // N
    int* deg     = (int*)(agg0 + N);       // N
    int* rs      = deg + N;                // N+1
    int* cursor  = rs + (N + 1);           // N
    int* csr     = cursor + N;             // E
    int* bsums   = csr + E;                // <=256
    float* partial = (float*)(bsums + 256);  // 256*H
    float* pooled  = partial + 256 * H;    // H

    // CSR build
    hipMemsetAsync(deg, 0, (size_t)N * sizeof(int), stream);
    hipMemsetAsync(cursor, 0, (size_t)N * sizeof(int), stream);
    count_deg_kernel<<<(E + 255) / 256, 256, 0, stream>>>(dst, deg, E);
    int nb = (N + 1023) / 1024;
    scan_block_kernel<<<nb, 1024, 0, stream>>>(deg, rs, bsums, N);
    scan_sums_kernel<<<1, 64, 0, stream>>>(bsums, nb, rs, N, E);
    add_offsets_kernel<<<nb, 1024, 0, stream>>>(rs, bsums, N);
    fill_csr_kernel<<<(E + 255) / 256, 256, 0, stream>>>(src, dst, rs, cursor, csr, E);

    // Weights -> bf16 transposed [layer][col][k]
    prep_w_kernel<<<256, 256, 0, stream>>>(Wl, Wr, Btg);

    // Layer 0: 1 -> H (bf16 out)
    agg0_kernel<<<(N + 255) / 256, 256, 0, stream>>>(node_feats, rs, csr, deg, agg0, N);
    expand0_kernel<<<((size_t)N * H + 255) / 256, 256, 0, stream>>>(node_feats, agg0, Wl0, bl0, Wr0, hA, N);

    // Layer 1: h=hA -> agg -> gemm -> hB
    aggregate_kernel<<<(N + 3) / 4, 256, 0, stream>>>(hA, rs, csr, deg, aggb, N);
    gemm_kernel<<<512, 256, 0, stream>>>(aggb, hA, Btg, bl, hB, N);

    // Layer 2: h=hB -> agg -> gemm -> hA
    aggregate_kernel<<<(N + 3) / 4, 256, 0, stream>>>(hB, rs, csr, deg, aggb, N);
    gemm_kernel<<<512, 256, 0, stream>>>(aggb, hB, Btg + 32768, bl + H, hA, N);

    // Pool over nodes (h = hA)
    pool_partial_kernel<<<256, 64, 0, stream>>>(hA, partial, N);
    pool_final_kernel<<<1, H, 0, stream>>>(partial, pooled, 256, 1.0f / (float)N);

    // Final MLP
    mlp_kernel<<<1, H, 0, stream>>>(pooled, Wv, bv, temp, tt, Wm1, bm1, Wm2, bm2, (float*)d_out);
}

// Round 3
// 486.482 us; speedup vs baseline: 3.1801x; 1.2998x over previous
//
#include <hip/hip_runtime.h>
#include <hip/hip_bf16.h>
#include <math.h>

#define H 128
#define BKT_SHIFT 9
#define BKT_NODES 512
#define CHUNK 4096   // edges per block in phase A/B

typedef __attribute__((ext_vector_type(8))) short short8;
typedef __attribute__((ext_vector_type(4))) float f32x4;

static __device__ __forceinline__ ushort f2b(float v) {
    union { float f; unsigned u; } x; x.f = v;
    unsigned r = x.u + 0x7fffu + ((x.u >> 16) & 1u);
    return (ushort)(r >> 16);
}
static __device__ __forceinline__ float b2f(ushort b) {
    union { unsigned u; float f; } x; x.u = ((unsigned)b) << 16;
    return x.f;
}

// ---------------- Bucketed CSR build ----------------
// Phase A: per-block histogram over coarse buckets (dst>>9), reserve per-block bases.

__global__ void bucket_hist_kernel(const int* __restrict__ dst, int e,
                                   int* __restrict__ bucketCount, int* __restrict__ blockBase) {
    __shared__ int hist[256];
    int t = threadIdx.x;
    hist[t] = 0;
    __syncthreads();
    int base = blockIdx.x * CHUNK;
    #pragma unroll
    for (int k = 0; k < CHUNK / 256; k++) {
        int i = base + k * 256 + t;
        if (i < e) atomicAdd(&hist[dst[i] >> BKT_SHIFT], 1);
    }
    __syncthreads();
    blockBase[blockIdx.x * 256 + t] = atomicAdd(&bucketCount[t], hist[t]);
}

// Scan bucket counts (serial, 256 entries) -> bucketBase; also rs[N]=E.

__global__ void bucket_scan_kernel(const int* __restrict__ bucketCount, int* __restrict__ bucketBase,
                                   int* __restrict__ rs, int n, int e) {
    if (threadIdx.x == 0 && blockIdx.x == 0) {
        int acc = 0;
        for (int i = 0; i < 256; i++) { bucketBase[i] = acc; acc += bucketCount[i]; }
        bucketBase[256] = acc;
        rs[n] = e;
    }
}

// Phase B: scatter (dst,src) pairs into bucket-grouped array (writes in ~128B runs per bucket).

__global__ void bucket_scatter_kernel(const int* __restrict__ src, const int* __restrict__ dst, int e,
                                      const int* __restrict__ bucketBase, const int* __restrict__ blockBase,
                                      int2* __restrict__ grouped) {
    __shared__ int cur[256];
    int t = threadIdx.x;
    cur[t] = bucketBase[t] + blockBase[blockIdx.x * 256 + t];
    __syncthreads();
    int base = blockIdx.x * CHUNK;
    #pragma unroll
    for (int k = 0; k < CHUNK / 256; k++) {
        int i = base + k * 256 + t;
        if (i < e) {
            int d = dst[i];
            int pos = atomicAdd(&cur[d >> BKT_SHIFT], 1);
            int2 p; p.x = d; p.y = src[i];
            grouped[pos] = p;
        }
    }
}

// Phase C: per-bucket exact CSR (LDS counters + LDS scan); all scatter writes stay in one CU/XCD.

__global__ void bucket_csr_kernel(const int2* __restrict__ grouped, const int* __restrict__ bucketBase,
                                  int* __restrict__ rs, int* __restrict__ csr, int n) {
    __shared__ int sdeg[BKT_NODES];
    __shared__ int sexcl[BKT_NODES];
    __shared__ int wsum[4];
    int b = blockIdx.x;
    int t = threadIdx.x;
    int nodeBase = b << BKT_SHIFT;
    int ebase = bucketBase[b], eend = bucketBase[b + 1];
    sdeg[t] = 0; sdeg[t + 256] = 0;
    __syncthreads();
    for (int e = ebase + t; e < eend; e += 256)
        atomicAdd(&sdeg[grouped[e].x - nodeBase], 1);
    __syncthreads();
    // scan 512 ints with 256 threads
    int lane = t & 63, wid = t >> 6;
    int v0 = sdeg[2 * t], v1 = sdeg[2 * t + 1];
    int p = v0 + v1;
    int x = p;
    #pragma unroll
    for (int off = 1; off < 64; off <<= 1) {
        int y = __shfl_up(x, off, 64);
        if (lane >= off) x += y;
    }
    if (lane == 63) wsum[wid] = x;
    __syncthreads();
    if (t == 0) {
        int acc = 0;
        #pragma unroll
        for (int w = 0; w < 4; w++) { int tmp = wsum[w]; wsum[w] = acc; acc += tmp; }
    }
    __syncthreads();
    int basep = wsum[wid] + x - p;
    sexcl[2 * t] = basep;
    sexcl[2 * t + 1] = basep + v0;
    // write rs
    int nodes = min(BKT_NODES, n - nodeBase);
    for (int i = t; i < nodes; i += 256) rs[nodeBase + i] = ebase + sexcl[i];
    // reuse sdeg as cursors
    sdeg[t] = 0; sdeg[t + 256] = 0;
    __syncthreads();
    for (int e = ebase + t; e < eend; e += 256) {
        int2 pr = grouped[e];
        int l = pr.x - nodeBase;
        int r = atomicAdd(&sdeg[l], 1);
        csr[ebase + sexcl[l] + r] = pr.y;
    }
}

// ---------------- Weight prep: Btg[layer][col][k] bf16, k<128 from Wl, k>=128 from Wr ----------------

__global__ void prep_w_kernel(const float* __restrict__ Wl, const float* __restrict__ Wr,
                              ushort* __restrict__ Btg) {
    int idx = blockIdx.x * 256 + threadIdx.x;   // 2*128*256 = 65536
    if (idx >= 65536) return;
    int l = idx >> 15;
    int col = (idx >> 8) & 127;
    int k = idx & 255;
    float v = (k < 128) ? Wl[l * H * H + k * H + col] : Wr[l * H * H + (k - 128) * H + col];
    Btg[idx] = f2b(v);
}

// ---------------- Layer 0 (in_dim = 1) ----------------

__global__ void agg0_kernel(const float* __restrict__ x, const int* __restrict__ rs,
                            const int* __restrict__ csr, float* __restrict__ agg0, int n) {
    int i = blockIdx.x * 256 + threadIdx.x;
    if (i >= n) return;
    int a = rs[i], b = rs[i + 1];
    float s = 0.f;
    for (int e = a; e < b; e++) s += x[csr[e]];
    agg0[i] = s / (float)max(b - a, 1);
}

__global__ void expand0_kernel(const float* __restrict__ x, const float* __restrict__ agg0,
                               const float* __restrict__ Wl0, const float* __restrict__ bl0,
                               const float* __restrict__ Wr0, ushort* __restrict__ hout, int n) {
    int idx = blockIdx.x * 256 + threadIdx.x;
    if (idx >= n * H) return;
    int i = idx >> 7, j = idx & (H - 1);
    float v = agg0[i] * Wl0[j] + bl0[j] + x[i] * Wr0[j];
    hout[idx] = f2b(fmaxf(v, 0.f));
}

// ---------------- Layer-1 aggregate, fused with layer-0 row reconstruction ----------------
// agg row i = (1/deg) sum_{nbr} relu(agg0[nbr]*Wl0 + bl0 + x[nbr]*Wr0): 8B gather per edge.

__global__ void aggregate1_kernel(const float* __restrict__ agg0, const float* __restrict__ x,
                                  const float* __restrict__ Wl0, const float* __restrict__ bl0,
                                  const float* __restrict__ Wr0,
                                  const int* __restrict__ rs, const int* __restrict__ csr,
                                  ushort* __restrict__ aggb, int n) {
    int node = blockIdx.x * 4 + (threadIdx.x >> 6);
    int lane = threadIdx.x & 63;
    if (node >= n) return;
    float wl0 = Wl0[2 * lane], wl1 = Wl0[2 * lane + 1];
    float wr0 = Wr0[2 * lane], wr1 = Wr0[2 * lane + 1];
    float b0 = bl0[2 * lane], b1 = bl0[2 * lane + 1];
    int a = rs[node], b = rs[node + 1];
    float s0 = 0.f, s1 = 0.f;
    int e = a;
    for (; e + 4 <= b; e += 4) {
        int n0 = csr[e], n1 = csr[e + 1], n2 = csr[e + 2], n3 = csr[e + 3];
        float g0 = agg0[n0], x0 = x[n0];
        float g1 = agg0[n1], x1 = x[n1];
        float g2 = agg0[n2], x2 = x[n2];
        float g3 = agg0[n3], x3 = x[n3];
        s0 += fmaxf(g0 * wl0 + x0 * wr0 + b0, 0.f) + fmaxf(g1 * wl0 + x1 * wr0 + b0, 0.f)
            + fmaxf(g2 * wl0 + x2 * wr0 + b0, 0.f) + fmaxf(g3 * wl0 + x3 * wr0 + b0, 0.f);
        s1 += fmaxf(g0 * wl1 + x0 * wr1 + b1, 0.f) + fmaxf(g1 * wl1 + x1 * wr1 + b1, 0.f)
            + fmaxf(g2 * wl1 + x2 * wr1 + b1, 0.f) + fmaxf(g3 * wl1 + x3 * wr1 + b1, 0.f);
    }
    for (; e < b; e++) {
        int nb_ = csr[e];
        float g = agg0[nb_], xx = x[nb_];
        s0 += fmaxf(g * wl0 + xx * wr0 + b0, 0.f);
        s1 += fmaxf(g * wl1 + xx * wr1 + b1, 0.f);
    }
    float inv = 1.f / (float)max(b - a, 1);
    aggb[(size_t)node * H + 2 * lane]     = f2b(s0 * inv);
    aggb[(size_t)node * H + 2 * lane + 1] = f2b(s1 * inv);
}

// ---------------- Layer-2 aggregate (CSR row gather mean), bf16 ----------------

__global__ void aggregate_kernel(const ushort* __restrict__ hb, const int* __restrict__ rs,
                                 const int* __restrict__ csr, ushort* __restrict__ aggb, int n) {
    int node = blockIdx.x * 4 + (threadIdx.x >> 6);
    int lane = threadIdx.x & 63;
    if (node >= n) return;
    int a = rs[node], b = rs[node + 1];
    float s0 = 0.f, s1 = 0.f;
    int e = a;
    for (; e + 4 <= b; e += 4) {
        int n0 = csr[e], n1 = csr[e + 1], n2 = csr[e + 2], n3 = csr[e + 3];
        ushort2 v0 = *(const ushort2*)(hb + (size_t)n0 * H + 2 * lane);
        ushort2 v1 = *(const ushort2*)(hb + (size_t)n1 * H + 2 * lane);
        ushort2 v2 = *(const ushort2*)(hb + (size_t)n2 * H + 2 * lane);
        ushort2 v3 = *(const ushort2*)(hb + (size_t)n3 * H + 2 * lane);
        s0 += b2f(v0.x) + b2f(v1.x) + b2f(v2.x) + b2f(v3.x);
        s1 += b2f(v0.y) + b2f(v1.y) + b2f(v2.y) + b2f(v3.y);
    }
    for (; e < b; e++) {
        int nb_ = csr[e];
        ushort2 v = *(const ushort2*)(hb + (size_t)nb_ * H + 2 * lane);
        s0 += b2f(v.x); s1 += b2f(v.y);
    }
    float inv = 1.f / (float)max(b - a, 1);
    aggb[(size_t)node * H + 2 * lane]     = f2b(s0 * inv);
    aggb[(size_t)node * H + 2 * lane + 1] = f2b(s1 * inv);
}

// ---------------- Fused dual GEMM: out = relu([agg|h] @ [Wl;Wr] + b), bf16 MFMA ----------------

__global__ __launch_bounds__(256, 2) void gemm_kernel(
    const ushort* __restrict__ aggb, const ushort* __restrict__ hb,
    const ushort* __restrict__ Btg,   // [128][256] bf16 for this layer
    const float* __restrict__ bias, ushort* __restrict__ out, int n) {
    __shared__ ushort Bt[128 * 256];  // 64 KB, [col][k] with kbyte ^= (col&7)<<4
    int tid = threadIdx.x;
    for (int c = tid; c < 4096; c += 256) {          // 4096 chunks of 16B
        int col = c >> 5;
        int kb = (c & 31) << 4;                       // byte offset along k
        short8 v = *(const short8*)(Btg + col * 256 + (kb >> 1));
        *(short8*)((char*)Bt + col * 512 + (kb ^ ((col & 7) << 4))) = v;
    }
    __syncthreads();

    int wave = tid >> 6, lane = tid & 63;
    int l15 = lane & 15;
    int lhi = lane >> 4;          // 0..3
    int klane = lhi * 8;          // element offset within 32-wide k-chunk

    for (int r0 = blockIdx.x * 64; r0 < n; r0 += gridDim.x * 64) {
        int row0 = r0 + wave * 16;
        int arow = row0 + l15;
        if (arow >= n) arow = n - 1;                  // clamp; store is masked

        f32x4 acc[8];
        #pragma unroll
        for (int c2 = 0; c2 < 8; c2++) acc[c2] = (f32x4){0.f, 0.f, 0.f, 0.f};

        #pragma unroll
        for (int s = 0; s < 8; s++) {
            const ushort* ap = (s < 4 ? aggb : hb) + (size_t)arow * H + (s & 3) * 32 + klane;
            short8 a = *(const short8*)ap;
            #pragma unroll
            for (int c2 = 0; c2 < 8; c2++) {
                int col = c2 * 16 + l15;
                int kb = s * 64 + lhi * 16;
                short8 b = *(const short8*)((char*)Bt + col * 512 + (kb ^ ((col & 7) << 4)));
                acc[c2] = __builtin_amdgcn_mfma_f32_16x16x32_bf16(a, b, acc[c2], 0, 0, 0);
            }
        }

        #pragma unroll
        for (int c2 = 0; c2 < 8; c2++) {
            int col = c2 * 16 + l15;
            float bj = bias[col];
            #pragma unroll
            for (int r = 0; r < 4; r++) {
                int row = row0 + lhi * 4 + r;
                if (row < n) out[(size_t)row * H + col] = f2b(fmaxf(acc[c2][r] + bj, 0.f));
            }
        }
    }
}

// ---------------- Pooling (fixed-order, deterministic) ----------------

__global__ void pool_partial_kernel(const ushort* __restrict__ h, float* __restrict__ partial, int n) {
    int w = blockIdx.x;            // 256 blocks of one wave
    int lane = threadIdx.x;        // 64
    float s0 = 0.f, s1 = 0.f;
    for (int r = w; r < n; r += 256) {
        ushort2 v = *(const ushort2*)(h + (size_t)r * H + 2 * lane);
        s0 += b2f(v.x); s1 += b2f(v.y);
    }
    partial[w * H + 2 * lane] = s0;
    partial[w * H + 2 * lane + 1] = s1;
}

__global__ void pool_final_kernel(const float* __restrict__ partial, float* __restrict__ pooled,
                                  int nb, float invn) {
    int f = threadIdx.x;
    float s = 0.f;
    for (int b = 0; b < nb; b++) s += partial[b * H + f];
    pooled[f] = s * invn;
}

// ---------------- Final MLP ----------------

__global__ void mlp_kernel(const float* __restrict__ pooled,
                           const float* __restrict__ Wv, const float* __restrict__ bv,
                           const float* __restrict__ temp, const float* __restrict__ tt,
                           const float* __restrict__ Wm1, const float* __restrict__ bm1,
                           const float* __restrict__ Wm2, const float* __restrict__ bm2,
                           float* __restrict__ out) {
    __shared__ float feat[66];
    __shared__ float red[2];
    int j = threadIdx.x;  // 128 threads
    if (j < 64) {
        float s = bv[j];
        for (int k = 0; k < H; k++) s += pooled[k] * Wv[k * 64 + j];
        feat[j] = s;
    }
    if (j == 64) feat[64] = temp[0];
    if (j == 65) feat[65] = tt[0];
    __syncthreads();
    float m = bm1[j];
    for (int k = 0; k < 66; k++) m += feat[k] * Wm1[k * H + j];
    m = fmaxf(m, 0.f);
    float p = m * Wm2[j];
    #pragma unroll
    for (int off = 32; off > 0; off >>= 1) p += __shfl_down(p, off, 64);
    if ((j & 63) == 0) red[j >> 6] = p;
    __syncthreads();
    if (j == 0) {
        float x = red[0] + red[1] + bm2[0];
        out[0] = (x > 20.f) ? x : log1pf(expf(x));
    }
}

// ---------------- Launch ----------------

extern "C" void kernel_launch(void* const* d_in, const int* in_sizes, int n_in,
                              void* d_out, int out_size, void* d_ws, size_t ws_size,
                              hipStream_t stream) {
    const float* node_feats = (const float*)d_in[0];
    const int* edge_index = (const int*)d_in[1];
    const float* temp = (const float*)d_in[3];
    const float* tt   = (const float*)d_in[4];
    const float* Wl0 = (const float*)d_in[5];
    const float* bl0 = (const float*)d_in[6];
    const float* Wr0 = (const float*)d_in[7];
    const float* Wl  = (const float*)d_in[8];
    const float* bl  = (const float*)d_in[9];
    const float* Wr  = (const float*)d_in[10];
    const float* Wv  = (const float*)d_in[11];
    const float* bv  = (const float*)d_in[12];
    const float* Wm1 = (const float*)d_in[13];
    const float* bm1 = (const float*)d_in[14];
    const float* Wm2 = (const float*)d_in[15];
    const float* bm2 = (const float*)d_in[16];

    const int N = in_sizes[0];
    const int E = in_sizes[1] / 2;
    const int* src = edge_index;
    const int* dst = edge_index + E;

    size_t NH = (size_t)N * H;
    ushort* hA   = (ushort*)d_ws;            // N*H bf16
    ushort* hB   = hA + NH;                  // N*H bf16
    ushort* aggb = hB + NH;                  // N*H bf16
    ushort* Btg  = aggb + NH;                // 2*128*256 bf16
    float* agg0  = (float*)(Btg + 65536);    // N f32 (N*4 % 8 == 0)
    int2* grouped = (int2*)(agg0 + N);       // E pairs (8B aligned)
    int* csr     = (int*)(grouped + E);      // E
    int* rs      = csr + E;                  // N+1
    int* bucketCount = rs + (N + 1);         // 256
    int* bucketBase  = bucketCount + 256;    // 257
    int* blockBase   = bucketBase + 257;     // NBLK*256
    int NBLK = (E + CHUNK - 1) / CHUNK;
    float* partial = (float*)(blockBase + NBLK * 256);  // 256*H
    float* pooled  = partial + 256 * H;      // H

    int NB = (N + BKT_NODES - 1) / BKT_NODES;

    // CSR build (bucketed)
    hipMemsetAsync(bucketCount, 0, 256 * sizeof(int), stream);
    bucket_hist_kernel<<<NBLK, 256, 0, stream>>>(dst, E, bucketCount, blockBase);
    bucket_scan_kernel<<<1, 64, 0, stream>>>(bucketCount, bucketBase, rs, N, E);
    bucket_scatter_kernel<<<NBLK, 256, 0, stream>>>(src, dst, E, bucketBase, blockBase, grouped);
    bucket_csr_kernel<<<NB, 256, 0, stream>>>(grouped, bucketBase, rs, csr, N);

    // Weights -> bf16 transposed [layer][col][k]
    prep_w_kernel<<<256, 256, 0, stream>>>(Wl, Wr, Btg);

    // Layer 0 scalar part
    agg0_kernel<<<(N + 255) / 256, 256, 0, stream>>>(node_feats, rs, csr, agg0, N);
    expand0_kernel<<<((size_t)N * H + 255) / 256, 256, 0, stream>>>(node_feats, agg0, Wl0, bl0, Wr0, hA, N);

    // Layer 1: aggregate (fused layer-0 row reconstruction) -> gemm -> hB
    aggregate1_kernel<<<(N + 3) / 4, 256, 0, stream>>>(agg0, node_feats, Wl0, bl0, Wr0, rs, csr, aggb, N);
    gemm_kernel<<<512, 256, 0, stream>>>(aggb, hA, Btg, bl, hB, N);

    // Layer 2: h=hB -> aggregate -> gemm -> hA
    aggregate_kernel<<<(N + 3) / 4, 256, 0, stream>>>(hB, rs, csr, aggb, N);
    gemm_kernel<<<512, 256, 0, stream>>>(aggb, hB, Btg + 32768, bl + H, hA, N);

    // Pool over nodes (h = hA)
    pool_partial_kernel<<<256, 64, 0, stream>>>(hA, partial, N);
    pool_final_kernel<<<1, H, 0, stream>>>(partial, pooled, 256, 1.0f / (float)N);

    // Final MLP
    mlp_kernel<<<1, H, 0, stream>>>(pooled, Wv, bv, temp, tt, Wm1, bm1, Wm2, bm2, (float*)d_out);
}

// Round 4
// 438.023 us; speedup vs baseline: 3.5319x; 1.1106x over previous
//
#include <hip/hip_runtime.h>
#include <hip/hip_bf16.h>
#include <math.h>

#define H 128
#define BKT_SHIFT 9
#define BKT_NODES 512
#define CHUNK 4096   // edges per block in phase A/B
#define GEMM_GRID 512

typedef __attribute__((ext_vector_type(8))) short short8;
typedef __attribute__((ext_vector_type(4))) float f32x4;

static __device__ __forceinline__ ushort f2b(float v) {
    union { float f; unsigned u; } x; x.f = v;
    unsigned r = x.u + 0x7fffu + ((x.u >> 16) & 1u);
    return (ushort)(r >> 16);
}
static __device__ __forceinline__ float b2f(ushort b) {
    union { unsigned u; float f; } x; x.u = ((unsigned)b) << 16;
    return x.f;
}

// ---------------- Bucketed CSR build ----------------

__global__ void bucket_hist_kernel(const int* __restrict__ dst, int e,
                                   int* __restrict__ bucketCount, int* __restrict__ blockBase) {
    __shared__ int hist[256];
    int t = threadIdx.x;
    hist[t] = 0;
    __syncthreads();
    int base = blockIdx.x * CHUNK;
    #pragma unroll
    for (int k = 0; k < CHUNK / 256; k++) {
        int i = base + k * 256 + t;
        if (i < e) atomicAdd(&hist[dst[i] >> BKT_SHIFT], 1);
    }
    __syncthreads();
    blockBase[blockIdx.x * 256 + t] = atomicAdd(&bucketCount[t], hist[t]);
}

__global__ void bucket_scan_kernel(const int* __restrict__ bucketCount, int* __restrict__ bucketBase,
                                   int* __restrict__ rs, int n, int e) {
    if (threadIdx.x == 0 && blockIdx.x == 0) {
        int acc = 0;
        for (int i = 0; i < 256; i++) { bucketBase[i] = acc; acc += bucketCount[i]; }
        bucketBase[256] = acc;
        rs[n] = e;
    }
}

__global__ void bucket_scatter_kernel(const int* __restrict__ src, const int* __restrict__ dst, int e,
                                      const int* __restrict__ bucketBase, const int* __restrict__ blockBase,
                                      int2* __restrict__ grouped) {
    __shared__ int cur[256];
    int t = threadIdx.x;
    cur[t] = bucketBase[t] + blockBase[blockIdx.x * 256 + t];
    __syncthreads();
    int base = blockIdx.x * CHUNK;
    #pragma unroll
    for (int k = 0; k < CHUNK / 256; k++) {
        int i = base + k * 256 + t;
        if (i < e) {
            int d = dst[i];
            int pos = atomicAdd(&cur[d >> BKT_SHIFT], 1);
            int2 p; p.x = d; p.y = src[i];
            grouped[pos] = p;
        }
    }
}

__global__ void bucket_csr_kernel(const int2* __restrict__ grouped, const int* __restrict__ bucketBase,
                                  int* __restrict__ rs, int* __restrict__ csr, int n) {
    __shared__ int sdeg[BKT_NODES];
    __shared__ int sexcl[BKT_NODES];
    __shared__ int wsum[4];
    int b = blockIdx.x;
    int t = threadIdx.x;
    int nodeBase = b << BKT_SHIFT;
    int ebase = bucketBase[b], eend = bucketBase[b + 1];
    sdeg[t] = 0; sdeg[t + 256] = 0;
    __syncthreads();
    for (int e = ebase + t; e < eend; e += 256)
        atomicAdd(&sdeg[grouped[e].x - nodeBase], 1);
    __syncthreads();
    int lane = t & 63, wid = t >> 6;
    int v0 = sdeg[2 * t], v1 = sdeg[2 * t + 1];
    int p = v0 + v1;
    int x = p;
    #pragma unroll
    for (int off = 1; off < 64; off <<= 1) {
        int y = __shfl_up(x, off, 64);
        if (lane >= off) x += y;
    }
    if (lane == 63) wsum[wid] = x;
    __syncthreads();
    if (t == 0) {
        int acc = 0;
        #pragma unroll
        for (int w = 0; w < 4; w++) { int tmp = wsum[w]; wsum[w] = acc; acc += tmp; }
    }
    __syncthreads();
    int basep = wsum[wid] + x - p;
    sexcl[2 * t] = basep;
    sexcl[2 * t + 1] = basep + v0;
    int nodes = min(BKT_NODES, n - nodeBase);
    for (int i = t; i < nodes; i += 256) rs[nodeBase + i] = ebase + sexcl[i];
    sdeg[t] = 0; sdeg[t + 256] = 0;
    __syncthreads();
    for (int e = ebase + t; e < eend; e += 256) {
        int2 pr = grouped[e];
        int l = pr.x - nodeBase;
        int r = atomicAdd(&sdeg[l], 1);
        csr[ebase + sexcl[l] + r] = pr.y;
    }
}

// ---------------- Weight prep ----------------

__global__ void prep_w_kernel(const float* __restrict__ Wl, const float* __restrict__ Wr,
                              ushort* __restrict__ Btg) {
    int idx = blockIdx.x * 256 + threadIdx.x;   // 2*128*256 = 65536
    if (idx >= 65536) return;
    int l = idx >> 15;
    int col = (idx >> 8) & 127;
    int k = idx & 255;
    float v = (k < 128) ? Wl[l * H * H + k * H + col] : Wr[l * H * H + (k - 128) * H + col];
    Btg[idx] = f2b(v);
}

// ---------------- Layer 0 (in_dim = 1) ----------------

__global__ void agg0_kernel(const float* __restrict__ x, const int* __restrict__ rs,
                            const int* __restrict__ csr, float* __restrict__ agg0, int n) {
    int i = blockIdx.x * 256 + threadIdx.x;
    if (i >= n) return;
    int a = rs[i], b = rs[i + 1];
    float s = 0.f;
    for (int e = a; e < b; e++) s += x[csr[e]];
    agg0[i] = s / (float)max(b - a, 1);
}

__global__ void expand0_kernel(const float* __restrict__ x, const float* __restrict__ agg0,
                               const float* __restrict__ Wl0, const float* __restrict__ bl0,
                               const float* __restrict__ Wr0, ushort* __restrict__ hout, int n) {
    int idx = blockIdx.x * 256 + threadIdx.x;
    if (idx >= n * H) return;
    int i = idx >> 7, j = idx & (H - 1);
    float v = agg0[i] * Wl0[j] + bl0[j] + x[i] * Wr0[j];
    hout[idx] = f2b(fmaxf(v, 0.f));
}

// ---------------- Layer-1 aggregate (fused layer-0 row reconstruction) ----------------

__global__ void aggregate1_kernel(const float* __restrict__ agg0, const float* __restrict__ x,
                                  const float* __restrict__ Wl0, const float* __restrict__ bl0,
                                  const float* __restrict__ Wr0,
                                  const int* __restrict__ rs, const int* __restrict__ csr,
                                  ushort* __restrict__ aggb, int n) {
    int node = blockIdx.x * 4 + (threadIdx.x >> 6);
    int lane = threadIdx.x & 63;
    if (node >= n) return;
    float wl0 = Wl0[2 * lane], wl1 = Wl0[2 * lane + 1];
    float wr0 = Wr0[2 * lane], wr1 = Wr0[2 * lane + 1];
    float b0 = bl0[2 * lane], b1 = bl0[2 * lane + 1];
    int a = rs[node], b = rs[node + 1];
    float s0 = 0.f, s1 = 0.f;
    int e = a;
    for (; e + 4 <= b; e += 4) {
        int n0 = csr[e], n1 = csr[e + 1], n2 = csr[e + 2], n3 = csr[e + 3];
        float g0 = agg0[n0], x0 = x[n0];
        float g1 = agg0[n1], x1 = x[n1];
        float g2 = agg0[n2], x2 = x[n2];
        float g3 = agg0[n3], x3 = x[n3];
        s0 += fmaxf(g0 * wl0 + x0 * wr0 + b0, 0.f) + fmaxf(g1 * wl0 + x1 * wr0 + b0, 0.f)
            + fmaxf(g2 * wl0 + x2 * wr0 + b0, 0.f) + fmaxf(g3 * wl0 + x3 * wr0 + b0, 0.f);
        s1 += fmaxf(g0 * wl1 + x0 * wr1 + b1, 0.f) + fmaxf(g1 * wl1 + x1 * wr1 + b1, 0.f)
            + fmaxf(g2 * wl1 + x2 * wr1 + b1, 0.f) + fmaxf(g3 * wl1 + x3 * wr1 + b1, 0.f);
    }
    for (; e < b; e++) {
        int nb_ = csr[e];
        float g = agg0[nb_], xx = x[nb_];
        s0 += fmaxf(g * wl0 + xx * wr0 + b0, 0.f);
        s1 += fmaxf(g * wl1 + xx * wr1 + b1, 0.f);
    }
    float inv = 1.f / (float)max(b - a, 1);
    aggb[(size_t)node * H + 2 * lane]     = f2b(s0 * inv);
    aggb[(size_t)node * H + 2 * lane + 1] = f2b(s1 * inv);
}

// ---------------- Layer-2 aggregate: 16 lanes/row x short8, 4 neighbors/wave-iter ----------------

__global__ void aggregate_kernel(const ushort* __restrict__ hb, const int* __restrict__ rs,
                                 const int* __restrict__ csr, ushort* __restrict__ aggb, int n) {
    int node = blockIdx.x * 4 + (threadIdx.x >> 6);
    int lane = threadIdx.x & 63;
    if (node >= n) return;
    int g = lane >> 4;        // neighbor slot 0..3
    int fl = lane & 15;       // feature block: 8*fl .. 8*fl+7
    int a = rs[node], b = rs[node + 1];
    float s[8] = {0.f, 0.f, 0.f, 0.f, 0.f, 0.f, 0.f, 0.f};
    int e = a;
    for (; e + 8 <= b; e += 8) {
        int n0 = csr[e + g], n1 = csr[e + 4 + g];
        short8 v0 = *(const short8*)(hb + (size_t)n0 * H + 8 * fl);
        short8 v1 = *(const short8*)(hb + (size_t)n1 * H + 8 * fl);
        #pragma unroll
        for (int j = 0; j < 8; j++) s[j] += b2f((ushort)v0[j]) + b2f((ushort)v1[j]);
    }
    for (; e + 4 <= b; e += 4) {
        int n0 = csr[e + g];
        short8 v0 = *(const short8*)(hb + (size_t)n0 * H + 8 * fl);
        #pragma unroll
        for (int j = 0; j < 8; j++) s[j] += b2f((ushort)v0[j]);
    }
    if (e < b && g < (b - e)) {
        int n0 = csr[e + g];
        short8 v0 = *(const short8*)(hb + (size_t)n0 * H + 8 * fl);
        #pragma unroll
        for (int j = 0; j < 8; j++) s[j] += b2f((ushort)v0[j]);
    }
    #pragma unroll
    for (int j = 0; j < 8; j++) {
        s[j] += __shfl_xor(s[j], 16, 64);
        s[j] += __shfl_xor(s[j], 32, 64);
    }
    if (lane < 16) {
        float inv = 1.f / (float)max(b - a, 1);
        short8 o;
        #pragma unroll
        for (int j = 0; j < 8; j++) o[j] = (short)f2b(s[j] * inv);
        *(short8*)(aggb + (size_t)node * H + 8 * fl) = o;
    }
}

// ---------------- Fused dual GEMM (+ optional fused pooling) ----------------
// out = relu([agg|h] @ [Wl;Wr] + b). POOL=true: skip store, emit per-block feature partials.

template<bool POOL>
__global__ __launch_bounds__(256, 2) void gemm_kernel(
    const ushort* __restrict__ aggb, const ushort* __restrict__ hb,
    const ushort* __restrict__ Btg,   // [128][256] bf16 for this layer
    const float* __restrict__ bias, ushort* __restrict__ out,
    float* __restrict__ partial, int n) {
    __shared__ ushort Bt[128 * 256];  // 64 KB, [col][k] with kbyte ^= (col&7)<<4
    __shared__ float wsumLds[4][8][64];
    int tid = threadIdx.x;
    for (int c = tid; c < 4096; c += 256) {
        int col = c >> 5;
        int kb = (c & 31) << 4;
        short8 v = *(const short8*)(Btg + col * 256 + (kb >> 1));
        *(short8*)((char*)Bt + col * 512 + (kb ^ ((col & 7) << 4))) = v;
    }
    __syncthreads();

    int wave = tid >> 6, lane = tid & 63;
    int l15 = lane & 15;
    int lhi = lane >> 4;
    int klane = lhi * 8;

    float fs[8];
    #pragma unroll
    for (int c2 = 0; c2 < 8; c2++) fs[c2] = 0.f;

    for (int r0 = blockIdx.x * 64; r0 < n; r0 += gridDim.x * 64) {
        int row0 = r0 + wave * 16;
        int arow = row0 + l15;
        if (arow >= n) arow = n - 1;

        f32x4 acc[8];
        #pragma unroll
        for (int c2 = 0; c2 < 8; c2++) acc[c2] = (f32x4){0.f, 0.f, 0.f, 0.f};

        #pragma unroll
        for (int s = 0; s < 8; s++) {
            const ushort* ap = (s < 4 ? aggb : hb) + (size_t)arow * H + (s & 3) * 32 + klane;
            short8 a = *(const short8*)ap;
            #pragma unroll
            for (int c2 = 0; c2 < 8; c2++) {
                int col = c2 * 16 + l15;
                int kb = s * 64 + lhi * 16;
                short8 b = *(const short8*)((char*)Bt + col * 512 + (kb ^ ((col & 7) << 4)));
                acc[c2] = __builtin_amdgcn_mfma_f32_16x16x32_bf16(a, b, acc[c2], 0, 0, 0);
            }
        }

        #pragma unroll
        for (int c2 = 0; c2 < 8; c2++) {
            int col = c2 * 16 + l15;
            float bj = bias[col];
            #pragma unroll
            for (int r = 0; r < 4; r++) {
                int row = row0 + lhi * 4 + r;
                if (row < n) {
                    float v = fmaxf(acc[c2][r] + bj, 0.f);
                    if (POOL) fs[c2] += v;
                    else out[(size_t)row * H + col] = f2b(v);
                }
            }
        }
    }

    if (POOL) {
        #pragma unroll
        for (int c2 = 0; c2 < 8; c2++) wsumLds[wave][c2][lane] = fs[c2];
        __syncthreads();
        if (tid < 128) {
            int c2 = tid >> 4, lo = tid & 15;
            float s = 0.f;
            #pragma unroll
            for (int w = 0; w < 4; w++)
                #pragma unroll
                for (int lh = 0; lh < 4; lh++)
                    s += wsumLds[w][c2][lh * 16 + lo];
            partial[blockIdx.x * H + tid] = s;
        }
    }
}

// ---------------- Final pooling reduce ----------------

__global__ void pool_final_kernel(const float* __restrict__ partial, float* __restrict__ pooled,
                                  int nb, float invn) {
    int f = threadIdx.x;  // 128
    float s = 0.f;
    for (int b = 0; b < nb; b++) s += partial[b * H + f];
    pooled[f] = s * invn;
}

// ---------------- Final MLP ----------------

__global__ void mlp_kernel(const float* __restrict__ pooled,
                           const float* __restrict__ Wv, const float* __restrict__ bv,
                           const float* __restrict__ temp, const float* __restrict__ tt,
                           const float* __restrict__ Wm1, const float* __restrict__ bm1,
                           const float* __restrict__ Wm2, const float* __restrict__ bm2,
                           float* __restrict__ out) {
    __shared__ float feat[66];
    __shared__ float red[2];
    int j = threadIdx.x;  // 128 threads
    if (j < 64) {
        float s = bv[j];
        for (int k = 0; k < H; k++) s += pooled[k] * Wv[k * 64 + j];
        feat[j] = s;
    }
    if (j == 64) feat[64] = temp[0];
    if (j == 65) feat[65] = tt[0];
    __syncthreads();
    float m = bm1[j];
    for (int k = 0; k < 66; k++) m += feat[k] * Wm1[k * H + j];
    m = fmaxf(m, 0.f);
    float p = m * Wm2[j];
    #pragma unroll
    for (int off = 32; off > 0; off >>= 1) p += __shfl_down(p, off, 64);
    if ((j & 63) == 0) red[j >> 6] = p;
    __syncthreads();
    if (j == 0) {
        float x = red[0] + red[1] + bm2[0];
        out[0] = (x > 20.f) ? x : log1pf(expf(x));
    }
}

// ---------------- Launch ----------------

extern "C" void kernel_launch(void* const* d_in, const int* in_sizes, int n_in,
                              void* d_out, int out_size, void* d_ws, size_t ws_size,
                              hipStream_t stream) {
    const float* node_feats = (const float*)d_in[0];
    const int* edge_index = (const int*)d_in[1];
    const float* temp = (const float*)d_in[3];
    const float* tt   = (const float*)d_in[4];
    const float* Wl0 = (const float*)d_in[5];
    const float* bl0 = (const float*)d_in[6];
    const float* Wr0 = (const float*)d_in[7];
    const float* Wl  = (const float*)d_in[8];
    const float* bl  = (const float*)d_in[9];
    const float* Wr  = (const float*)d_in[10];
    const float* Wv  = (const float*)d_in[11];
    const float* bv  = (const float*)d_in[12];
    const float* Wm1 = (const float*)d_in[13];
    const float* bm1 = (const float*)d_in[14];
    const float* Wm2 = (const float*)d_in[15];
    const float* bm2 = (const float*)d_in[16];

    const int N = in_sizes[0];
    const int E = in_sizes[1] / 2;
    const int* src = edge_index;
    const int* dst = edge_index + E;

    size_t NH = (size_t)N * H;
    ushort* hA   = (ushort*)d_ws;            // N*H bf16
    ushort* hB   = hA + NH;                  // N*H bf16
    ushort* aggb = hB + NH;                  // N*H bf16
    ushort* Btg  = aggb + NH;                // 2*128*256 bf16
    float* agg0  = (float*)(Btg + 65536);    // N f32
    int2* grouped = (int2*)(agg0 + N);       // E pairs
    int* csr     = (int*)(grouped + E);      // E
    int* rs      = csr + E;                  // N+1
    int* bucketCount = rs + (N + 1);         // 256
    int* bucketBase  = bucketCount + 256;    // 257
    int* blockBase   = bucketBase + 257;     // NBLK*256
    int NBLK = (E + CHUNK - 1) / CHUNK;
    float* partial = (float*)(blockBase + NBLK * 256);  // GEMM_GRID*H
    float* pooled  = partial + GEMM_GRID * H;           // H

    int NB = (N + BKT_NODES - 1) / BKT_NODES;

    // CSR build (bucketed)
    hipMemsetAsync(bucketCount, 0, 256 * sizeof(int), stream);
    bucket_hist_kernel<<<NBLK, 256, 0, stream>>>(dst, E, bucketCount, blockBase);
    bucket_scan_kernel<<<1, 64, 0, stream>>>(bucketCount, bucketBase, rs, N, E);
    bucket_scatter_kernel<<<NBLK, 256, 0, stream>>>(src, dst, E, bucketBase, blockBase, grouped);
    bucket_csr_kernel<<<NB, 256, 0, stream>>>(grouped, bucketBase, rs, csr, N);

    // Weights -> bf16 transposed [layer][col][k]
    prep_w_kernel<<<256, 256, 0, stream>>>(Wl, Wr, Btg);

    // Layer 0 scalar part
    agg0_kernel<<<(N + 255) / 256, 256, 0, stream>>>(node_feats, rs, csr, agg0, N);
    expand0_kernel<<<((size_t)N * H + 255) / 256, 256, 0, stream>>>(node_feats, agg0, Wl0, bl0, Wr0, hA, N);

    // Layer 1: aggregate (fused layer-0 reconstruction) -> gemm -> hB
    aggregate1_kernel<<<(N + 3) / 4, 256, 0, stream>>>(agg0, node_feats, Wl0, bl0, Wr0, rs, csr, aggb, N);
    gemm_kernel<false><<<GEMM_GRID, 256, 0, stream>>>(aggb, hA, Btg, bl, hB, nullptr, N);

    // Layer 2: aggregate -> gemm (fused pooling, no h store)
    aggregate_kernel<<<(N + 3) / 4, 256, 0, stream>>>(hB, rs, csr, aggb, N);
    gemm_kernel<true><<<GEMM_GRID, 256, 0, stream>>>(aggb, hB, Btg + 32768, bl + H, nullptr, partial, N);

    // Final pooling reduce + MLP
    pool_final_kernel<<<1, H, 0, stream>>>(partial, pooled, GEMM_GRID, 1.0f / (float)N);
    mlp_kernel<<<1, H, 0, stream>>>(pooled, Wv, bv, temp, tt, Wm1, bm1, Wm2, bm2, (float*)d_out);
}

// Round 6
// 322.920 us; speedup vs baseline: 4.7909x; 1.3564x over previous
//
#include <hip/hip_runtime.h>
#include <hip/hip_bf16.h>
#include <math.h>

#define H 128
#define BKT_SHIFT 9
#define BKT_NODES 512
#define CHUNK 4096   // edges per block in phase A/B
#define GEMM_GRID 512

typedef __attribute__((ext_vector_type(8))) short short8;
typedef __attribute__((ext_vector_type(4))) float f32x4;

static __device__ __forceinline__ ushort f2b(float v) {
    union { float f; unsigned u; } x; x.f = v;
    unsigned r = x.u + 0x7fffu + ((x.u >> 16) & 1u);
    return (ushort)(r >> 16);
}
static __device__ __forceinline__ float b2f(ushort b) {
    union { unsigned u; float f; } x; x.u = ((unsigned)b) << 16;
    return x.f;
}

// ---------------- Bucketed CSR build ----------------

__global__ void bucket_hist_kernel(const int* __restrict__ dst, int e,
                                   int* __restrict__ bucketCount, int* __restrict__ blockBase) {
    __shared__ int hist[256];
    int t = threadIdx.x;
    hist[t] = 0;
    __syncthreads();
    int base = blockIdx.x * CHUNK;
    #pragma unroll
    for (int k = 0; k < CHUNK / 256; k++) {
        int i = base + k * 256 + t;
        if (i < e) atomicAdd(&hist[dst[i] >> BKT_SHIFT], 1);
    }
    __syncthreads();
    blockBase[blockIdx.x * 256 + t] = atomicAdd(&bucketCount[t], hist[t]);
}

__global__ void bucket_scan_kernel(const int* __restrict__ bucketCount, int* __restrict__ bucketBase,
                                   int* __restrict__ rs, int n, int e) {
    if (threadIdx.x == 0 && blockIdx.x == 0) {
        int acc = 0;
        for (int i = 0; i < 256; i++) { bucketBase[i] = acc; acc += bucketCount[i]; }
        bucketBase[256] = acc;
        rs[n] = e;
    }
}

__global__ void bucket_scatter_kernel(const int* __restrict__ src, const int* __restrict__ dst, int e,
                                      const int* __restrict__ bucketBase, const int* __restrict__ blockBase,
                                      int2* __restrict__ grouped) {
    __shared__ int cur[256];
    int t = threadIdx.x;
    cur[t] = bucketBase[t] + blockBase[blockIdx.x * 256 + t];
    __syncthreads();
    int base = blockIdx.x * CHUNK;
    #pragma unroll
    for (int k = 0; k < CHUNK / 256; k++) {
        int i = base + k * 256 + t;
        if (i < e) {
            int d = dst[i];
            int pos = atomicAdd(&cur[d >> BKT_SHIFT], 1);
            int2 p; p.x = d; p.y = src[i];
            grouped[pos] = p;
        }
    }
}

__global__ void bucket_csr_kernel(const int2* __restrict__ grouped, const int* __restrict__ bucketBase,
                                  int* __restrict__ rs, int* __restrict__ csr, int n) {
    __shared__ int sdeg[BKT_NODES];
    __shared__ int sexcl[BKT_NODES];
    __shared__ int wsum[4];
    int b = blockIdx.x;
    int t = threadIdx.x;
    int nodeBase = b << BKT_SHIFT;
    int ebase = bucketBase[b], eend = bucketBase[b + 1];
    sdeg[t] = 0; sdeg[t + 256] = 0;
    __syncthreads();
    for (int e = ebase + t; e < eend; e += 256)
        atomicAdd(&sdeg[grouped[e].x - nodeBase], 1);
    __syncthreads();
    int lane = t & 63, wid = t >> 6;
    int v0 = sdeg[2 * t], v1 = sdeg[2 * t + 1];
    int p = v0 + v1;
    int x = p;
    #pragma unroll
    for (int off = 1; off < 64; off <<= 1) {
        int y = __shfl_up(x, off, 64);
        if (lane >= off) x += y;
    }
    if (lane == 63) wsum[wid] = x;
    __syncthreads();
    if (t == 0) {
        int acc = 0;
        #pragma unroll
        for (int w = 0; w < 4; w++) { int tmp = wsum[w]; wsum[w] = acc; acc += tmp; }
    }
    __syncthreads();
    int basep = wsum[wid] + x - p;
    sexcl[2 * t] = basep;
    sexcl[2 * t + 1] = basep + v0;
    int nodes = min(BKT_NODES, n - nodeBase);
    for (int i = t; i < nodes; i += 256) rs[nodeBase + i] = ebase + sexcl[i];
    sdeg[t] = 0; sdeg[t + 256] = 0;
    __syncthreads();
    for (int e = ebase + t; e < eend; e += 256) {
        int2 pr = grouped[e];
        int l = pr.x - nodeBase;
        int r = atomicAdd(&sdeg[l], 1);
        csr[ebase + sexcl[l] + r] = pr.y;
    }
}

// ---------------- Weight prep ----------------

__global__ void prep_w_kernel(const float* __restrict__ Wl, const float* __restrict__ Wr,
                              ushort* __restrict__ Btg) {
    int idx = blockIdx.x * 256 + threadIdx.x;   // 2*128*256 = 65536
    if (idx >= 65536) return;
    int l = idx >> 15;
    int col = (idx >> 8) & 127;
    int k = idx & 255;
    float v = (k < 128) ? Wl[l * H * H + k * H + col] : Wr[l * H * H + (k - 128) * H + col];
    Btg[idx] = f2b(v);
}

// ---------------- Layer 0 (in_dim = 1) ----------------

__global__ void agg0_kernel(const float* __restrict__ x, const int* __restrict__ rs,
                            const int* __restrict__ csr, float* __restrict__ agg0, int n) {
    int i = blockIdx.x * 256 + threadIdx.x;
    if (i >= n) return;
    int a = rs[i], b = rs[i + 1];
    float s = 0.f;
    for (int e = a; e < b; e++) s += x[csr[e]];
    agg0[i] = s / (float)max(b - a, 1);
}

__global__ void expand0_kernel(const float* __restrict__ x, const float* __restrict__ agg0,
                               const float* __restrict__ Wl0, const float* __restrict__ bl0,
                               const float* __restrict__ Wr0, ushort* __restrict__ hout, int n) {
    int idx = blockIdx.x * 256 + threadIdx.x;
    if (idx >= n * H) return;
    int i = idx >> 7, j = idx & (H - 1);
    float v = agg0[i] * Wl0[j] + bl0[j] + x[i] * Wr0[j];
    hout[idx] = f2b(fmaxf(v, 0.f));
}

// ---------------- Layer-1 aggregate (fused layer-0 row reconstruction) ----------------

__global__ void aggregate1_kernel(const float* __restrict__ agg0, const float* __restrict__ x,
                                  const float* __restrict__ Wl0, const float* __restrict__ bl0,
                                  const float* __restrict__ Wr0,
                                  const int* __restrict__ rs, const int* __restrict__ csr,
                                  ushort* __restrict__ aggb, int n) {
    int node = blockIdx.x * 4 + (threadIdx.x >> 6);
    int lane = threadIdx.x & 63;
    if (node >= n) return;
    float wl0 = Wl0[2 * lane], wl1 = Wl0[2 * lane + 1];
    float wr0 = Wr0[2 * lane], wr1 = Wr0[2 * lane + 1];
    float b0 = bl0[2 * lane], b1 = bl0[2 * lane + 1];
    int a = rs[node], b = rs[node + 1];
    float s0 = 0.f, s1 = 0.f;
    int e = a;
    for (; e + 4 <= b; e += 4) {
        int n0 = csr[e], n1 = csr[e + 1], n2 = csr[e + 2], n3 = csr[e + 3];
        float g0 = agg0[n0], x0 = x[n0];
        float g1 = agg0[n1], x1 = x[n1];
        float g2 = agg0[n2], x2 = x[n2];
        float g3 = agg0[n3], x3 = x[n3];
        s0 += fmaxf(g0 * wl0 + x0 * wr0 + b0, 0.f) + fmaxf(g1 * wl0 + x1 * wr0 + b0, 0.f)
            + fmaxf(g2 * wl0 + x2 * wr0 + b0, 0.f) + fmaxf(g3 * wl0 + x3 * wr0 + b0, 0.f);
        s1 += fmaxf(g0 * wl1 + x0 * wr1 + b1, 0.f) + fmaxf(g1 * wl1 + x1 * wr1 + b1, 0.f)
            + fmaxf(g2 * wl1 + x2 * wr1 + b1, 0.f) + fmaxf(g3 * wl1 + x3 * wr1 + b1, 0.f);
    }
    for (; e < b; e++) {
        int nb_ = csr[e];
        float g = agg0[nb_], xx = x[nb_];
        s0 += fmaxf(g * wl0 + xx * wr0 + b0, 0.f);
        s1 += fmaxf(g * wl1 + xx * wr1 + b1, 0.f);
    }
    float inv = 1.f / (float)max(b - a, 1);
    aggb[(size_t)node * H + 2 * lane]     = f2b(s0 * inv);
    aggb[(size_t)node * H + 2 * lane + 1] = f2b(s1 * inv);
}

// ---------------- Layer-2 aggregate: 16 lanes/row x short8, 4 neighbors/wave-iter ----------------

__global__ void aggregate_kernel(const ushort* __restrict__ hb, const int* __restrict__ rs,
                                 const int* __restrict__ csr, ushort* __restrict__ aggb, int n) {
    int node = blockIdx.x * 4 + (threadIdx.x >> 6);
    int lane = threadIdx.x & 63;
    if (node >= n) return;
    int g = lane >> 4;        // neighbor slot 0..3
    int fl = lane & 15;       // feature block: 8*fl .. 8*fl+7
    int a = rs[node], b = rs[node + 1];
    float s[8] = {0.f, 0.f, 0.f, 0.f, 0.f, 0.f, 0.f, 0.f};
    int e = a;
    for (; e + 8 <= b; e += 8) {
        int n0 = csr[e + g], n1 = csr[e + 4 + g];
        short8 v0 = *(const short8*)(hb + (size_t)n0 * H + 8 * fl);
        short8 v1 = *(const short8*)(hb + (size_t)n1 * H + 8 * fl);
        #pragma unroll
        for (int j = 0; j < 8; j++) s[j] += b2f((ushort)v0[j]) + b2f((ushort)v1[j]);
    }
    for (; e + 4 <= b; e += 4) {
        int n0 = csr[e + g];
        short8 v0 = *(const short8*)(hb + (size_t)n0 * H + 8 * fl);
        #pragma unroll
        for (int j = 0; j < 8; j++) s[j] += b2f((ushort)v0[j]);
    }
    if (e < b && g < (b - e)) {
        int n0 = csr[e + g];
        short8 v0 = *(const short8*)(hb + (size_t)n0 * H + 8 * fl);
        #pragma unroll
        for (int j = 0; j < 8; j++) s[j] += b2f((ushort)v0[j]);
    }
    #pragma unroll
    for (int j = 0; j < 8; j++) {
        s[j] += __shfl_xor(s[j], 16, 64);
        s[j] += __shfl_xor(s[j], 32, 64);
    }
    if (lane < 16) {
        float inv = 1.f / (float)max(b - a, 1);
        short8 o;
        #pragma unroll
        for (int j = 0; j < 8; j++) o[j] = (short)f2b(s[j] * inv);
        *(short8*)(aggb + (size_t)node * H + 8 * fl) = o;
    }
}

// ---------------- Fused dual GEMM (+ optional fused pooling) ----------------
// out = relu([agg|h] @ [Wl;Wr] + b). POOL=true: skip store, emit per-block partials transposed.

template<bool POOL>
__global__ __launch_bounds__(256, 2) void gemm_kernel(
    const ushort* __restrict__ aggb, const ushort* __restrict__ hb,
    const ushort* __restrict__ Btg,   // [128][256] bf16 for this layer
    const float* __restrict__ bias, ushort* __restrict__ out,
    float* __restrict__ partial, int nblk, int n) {
    __shared__ ushort Bt[128 * 256];  // 64 KB, [col][k] with kbyte ^= (col&7)<<4
    __shared__ float wsumLds[4][8][64];
    int tid = threadIdx.x;
    for (int c = tid; c < 4096; c += 256) {
        int col = c >> 5;
        int kb = (c & 31) << 4;
        short8 v = *(const short8*)(Btg + col * 256 + (kb >> 1));
        *(short8*)((char*)Bt + col * 512 + (kb ^ ((col & 7) << 4))) = v;
    }
    __syncthreads();

    int wave = tid >> 6, lane = tid & 63;
    int l15 = lane & 15;
    int lhi = lane >> 4;
    int klane = lhi * 8;

    float fs[8];
    #pragma unroll
    for (int c2 = 0; c2 < 8; c2++) fs[c2] = 0.f;

    for (int r0 = blockIdx.x * 64; r0 < n; r0 += nblk * 64) {
        int row0 = r0 + wave * 16;
        int arow = row0 + l15;
        if (arow >= n) arow = n - 1;

        f32x4 acc[8];
        #pragma unroll
        for (int c2 = 0; c2 < 8; c2++) acc[c2] = (f32x4){0.f, 0.f, 0.f, 0.f};

        #pragma unroll
        for (int s = 0; s < 8; s++) {
            const ushort* ap = (s < 4 ? aggb : hb) + (size_t)arow * H + (s & 3) * 32 + klane;
            short8 a = *(const short8*)ap;
            #pragma unroll
            for (int c2 = 0; c2 < 8; c2++) {
                int col = c2 * 16 + l15;
                int kb = s * 64 + lhi * 16;
                short8 b = *(const short8*)((char*)Bt + col * 512 + (kb ^ ((col & 7) << 4)));
                acc[c2] = __builtin_amdgcn_mfma_f32_16x16x32_bf16(a, b, acc[c2], 0, 0, 0);
            }
        }

        #pragma unroll
        for (int c2 = 0; c2 < 8; c2++) {
            int col = c2 * 16 + l15;
            float bj = bias[col];
            #pragma unroll
            for (int r = 0; r < 4; r++) {
                int row = row0 + lhi * 4 + r;
                if (row < n) {
                    float v = fmaxf(acc[c2][r] + bj, 0.f);
                    if (POOL) fs[c2] += v;
                    else out[(size_t)row * H + col] = f2b(v);
                }
            }
        }
    }

    if (POOL) {
        #pragma unroll
        for (int c2 = 0; c2 < 8; c2++) wsumLds[wave][c2][lane] = fs[c2];
        __syncthreads();
        if (tid < 128) {
            int c2 = tid >> 4, lo = tid & 15;
            float s = 0.f;
            #pragma unroll
            for (int w = 0; w < 4; w++)
                #pragma unroll
                for (int lh = 0; lh < 4; lh++)
                    s += wsumLds[w][c2][lh * 16 + lo];
            // transposed: partial[feature][block] for coalesced final reduce
            partial[tid * nblk + blockIdx.x] = s;
        }
    }
}

// ---------------- Final pooling reduce: one wave per feature, no LDS ----------------

__global__ void pool_reduce_kernel(const float* __restrict__ partial, float* __restrict__ pooled,
                                   int nb, float invn) {
    int j = blockIdx.x;      // feature
    int t = threadIdx.x;     // 64 (one wave)
    float s = 0.f;
    for (int b = t; b < nb; b += 64) s += partial[j * nb + b];
    #pragma unroll
    for (int off = 32; off > 0; off >>= 1) s += __shfl_down(s, off, 64);
    if (t == 0) pooled[j] = s * invn;
}

// ---------------- Final MLP ----------------

__global__ void mlp_kernel(const float* __restrict__ pooled,
                           const float* __restrict__ Wv, const float* __restrict__ bv,
                           const float* __restrict__ temp, const float* __restrict__ tt,
                           const float* __restrict__ Wm1, const float* __restrict__ bm1,
                           const float* __restrict__ Wm2, const float* __restrict__ bm2,
                           float* __restrict__ out) {
    __shared__ float feat[66];
    __shared__ float red[2];
    int j = threadIdx.x;  // 128 threads
    if (j < 64) {
        float s = bv[j];
        for (int k = 0; k < H; k++) s += pooled[k] * Wv[k * 64 + j];
        feat[j] = s;
    }
    if (j == 64) feat[64] = temp[0];
    if (j == 65) feat[65] = tt[0];
    __syncthreads();
    float m = bm1[j];
    for (int k = 0; k < 66; k++) m += feat[k] * Wm1[k * H + j];
    m = fmaxf(m, 0.f);
    float p = m * Wm2[j];
    #pragma unroll
    for (int off = 32; off > 0; off >>= 1) p += __shfl_down(p, off, 64);
    if ((j & 63) == 0) red[j >> 6] = p;
    __syncthreads();
    if (j == 0) {
        float x = red[0] + red[1] + bm2[0];
        out[0] = (x > 20.f) ? x : log1pf(expf(x));
    }
}

// ---------------- Launch ----------------

extern "C" void kernel_launch(void* const* d_in, const int* in_sizes, int n_in,
                              void* d_out, int out_size, void* d_ws, size_t ws_size,
                              hipStream_t stream) {
    const float* node_feats = (const float*)d_in[0];
    const int* edge_index = (const int*)d_in[1];
    const float* temp = (const float*)d_in[3];
    const float* tt   = (const float*)d_in[4];
    const float* Wl0 = (const float*)d_in[5];
    const float* bl0 = (const float*)d_in[6];
    const float* Wr0 = (const float*)d_in[7];
    const float* Wl  = (const float*)d_in[8];
    const float* bl  = (const float*)d_in[9];
    const float* Wr  = (const float*)d_in[10];
    const float* Wv  = (const float*)d_in[11];
    const float* bv  = (const float*)d_in[12];
    const float* Wm1 = (const float*)d_in[13];
    const float* bm1 = (const float*)d_in[14];
    const float* Wm2 = (const float*)d_in[15];
    const float* bm2 = (const float*)d_in[16];

    const int N = in_sizes[0];
    const int E = in_sizes[1] / 2;
    const int* src = edge_index;
    const int* dst = edge_index + E;

    size_t NH = (size_t)N * H;
    ushort* hA   = (ushort*)d_ws;            // N*H bf16
    ushort* hB   = hA + NH;                  // N*H bf16
    ushort* aggb = hB + NH;                  // N*H bf16
    ushort* Btg  = aggb + NH;                // 2*128*256 bf16
    float* agg0  = (float*)(Btg + 65536);    // N f32
    int2* grouped = (int2*)(agg0 + N);       // E pairs
    int* csr     = (int*)(grouped + E);      // E
    int* rs      = csr + E;                  // N+1
    int* bucketCount = rs + (N + 1);         // 256
    int* bucketBase  = bucketCount + 256;    // 257
    int* blockBase   = bucketBase + 257;     // NBLK*256
    int NBLK = (E + CHUNK - 1) / CHUNK;
    float* partial = (float*)(blockBase + NBLK * 256);  // H*GEMM_GRID (transposed)
    float* pooled  = partial + (size_t)H * GEMM_GRID;   // H

    int NB = (N + BKT_NODES - 1) / BKT_NODES;

    // CSR build (bucketed)
    hipMemsetAsync(bucketCount, 0, 256 * sizeof(int), stream);
    bucket_hist_kernel<<<NBLK, 256, 0, stream>>>(dst, E, bucketCount, blockBase);
    bucket_scan_kernel<<<1, 64, 0, stream>>>(bucketCount, bucketBase, rs, N, E);
    bucket_scatter_kernel<<<NBLK, 256, 0, stream>>>(src, dst, E, bucketBase, blockBase, grouped);
    bucket_csr_kernel<<<NB, 256, 0, stream>>>(grouped, bucketBase, rs, csr, N);

    // Weights -> bf16 transposed [layer][col][k]
    prep_w_kernel<<<256, 256, 0, stream>>>(Wl, Wr, Btg);

    // Layer 0 scalar part
    agg0_kernel<<<(N + 255) / 256, 256, 0, stream>>>(node_feats, rs, csr, agg0, N);
    expand0_kernel<<<((size_t)N * H + 255) / 256, 256, 0, stream>>>(node_feats, agg0, Wl0, bl0, Wr0, hA, N);

    // Layer 1: aggregate (fused layer-0 reconstruction) -> gemm -> hB
    aggregate1_kernel<<<(N + 3) / 4, 256, 0, stream>>>(agg0, node_feats, Wl0, bl0, Wr0, rs, csr, aggb, N);
    gemm_kernel<false><<<GEMM_GRID, 256, 0, stream>>>(aggb, hA, Btg, bl, hB, nullptr, GEMM_GRID, N);

    // Layer 2: aggregate -> gemm (fused pooling, no h store)
    aggregate_kernel<<<(N + 3) / 4, 256, 0, stream>>>(hB, rs, csr, aggb, N);
    gemm_kernel<true><<<GEMM_GRID, 256, 0, stream>>>(aggb, hB, Btg + 32768, bl + H, nullptr, partial, GEMM_GRID, N);

    // Final pooling reduce + MLP
    pool_reduce_kernel<<<H, 64, 0, stream>>>(partial, pooled, GEMM_GRID, 1.0f / (float)N);
    mlp_kernel<<<1, H, 0, stream>>>(pooled, Wv, bv, temp, tt, Wm1, bm1, Wm2, bm2, (float*)d_out);
}

// Round 7
// 278.183 us; speedup vs baseline: 5.5613x; 1.1608x over previous
//
#include <hip/hip_runtime.h>
#include <hip/hip_bf16.h>
#include <math.h>

#define H 128
#define BKT_SHIFT 9
#define BKT_NODES 512
#define CHUNK 4096   // edges per block in phase A/B
#define GEMM_GRID 512

typedef __attribute__((ext_vector_type(8))) short short8;
typedef __attribute__((ext_vector_type(4))) float f32x4;

static __device__ __forceinline__ ushort f2b(float v) {
    union { float f; unsigned u; } x; x.f = v;
    unsigned r = x.u + 0x7fffu + ((x.u >> 16) & 1u);
    return (ushort)(r >> 16);
}
static __device__ __forceinline__ float b2f(ushort b) {
    union { unsigned u; float f; } x; x.u = ((unsigned)b) << 16;
    return x.f;
}

// ---------------- Bucketed CSR build ----------------

__global__ void bucket_hist_kernel(const int* __restrict__ dst, int e,
                                   int* __restrict__ bucketCount, int* __restrict__ blockBase) {
    __shared__ int hist[256];
    int t = threadIdx.x;
    hist[t] = 0;
    __syncthreads();
    int base = blockIdx.x * CHUNK;
    #pragma unroll
    for (int k = 0; k < CHUNK / 256; k++) {
        int i = base + k * 256 + t;
        if (i < e) atomicAdd(&hist[dst[i] >> BKT_SHIFT], 1);
    }
    __syncthreads();
    blockBase[blockIdx.x * 256 + t] = atomicAdd(&bucketCount[t], hist[t]);
}

__global__ void bucket_scan_kernel(const int* __restrict__ bucketCount, int* __restrict__ bucketBase,
                                   int* __restrict__ rs, int n, int e) {
    if (threadIdx.x == 0 && blockIdx.x == 0) {
        int acc = 0;
        for (int i = 0; i < 256; i++) { bucketBase[i] = acc; acc += bucketCount[i]; }
        bucketBase[256] = acc;
        rs[n] = e;
    }
}

__global__ void bucket_scatter_kernel(const int* __restrict__ src, const int* __restrict__ dst, int e,
                                      const int* __restrict__ bucketBase, const int* __restrict__ blockBase,
                                      int2* __restrict__ grouped) {
    __shared__ int cur[256];
    int t = threadIdx.x;
    cur[t] = bucketBase[t] + blockBase[blockIdx.x * 256 + t];
    __syncthreads();
    int base = blockIdx.x * CHUNK;
    #pragma unroll
    for (int k = 0; k < CHUNK / 256; k++) {
        int i = base + k * 256 + t;
        if (i < e) {
            int d = dst[i];
            int pos = atomicAdd(&cur[d >> BKT_SHIFT], 1);
            int2 p; p.x = d; p.y = src[i];
            grouped[pos] = p;
        }
    }
}

__global__ void bucket_csr_kernel(const int2* __restrict__ grouped, const int* __restrict__ bucketBase,
                                  int* __restrict__ rs, int* __restrict__ csr, int n) {
    __shared__ int sdeg[BKT_NODES];
    __shared__ int sexcl[BKT_NODES];
    __shared__ int wsum[4];
    int b = blockIdx.x;
    int t = threadIdx.x;
    int nodeBase = b << BKT_SHIFT;
    int ebase = bucketBase[b], eend = bucketBase[b + 1];
    sdeg[t] = 0; sdeg[t + 256] = 0;
    __syncthreads();
    for (int e = ebase + t; e < eend; e += 256)
        atomicAdd(&sdeg[grouped[e].x - nodeBase], 1);
    __syncthreads();
    int lane = t & 63, wid = t >> 6;
    int v0 = sdeg[2 * t], v1 = sdeg[2 * t + 1];
    int p = v0 + v1;
    int x = p;
    #pragma unroll
    for (int off = 1; off < 64; off <<= 1) {
        int y = __shfl_up(x, off, 64);
        if (lane >= off) x += y;
    }
    if (lane == 63) wsum[wid] = x;
    __syncthreads();
    if (t == 0) {
        int acc = 0;
        #pragma unroll
        for (int w = 0; w < 4; w++) { int tmp = wsum[w]; wsum[w] = acc; acc += tmp; }
    }
    __syncthreads();
    int basep = wsum[wid] + x - p;
    sexcl[2 * t] = basep;
    sexcl[2 * t + 1] = basep + v0;
    int nodes = min(BKT_NODES, n - nodeBase);
    for (int i = t; i < nodes; i += 256) rs[nodeBase + i] = ebase + sexcl[i];
    sdeg[t] = 0; sdeg[t + 256] = 0;
    __syncthreads();
    for (int e = ebase + t; e < eend; e += 256) {
        int2 pr = grouped[e];
        int l = pr.x - nodeBase;
        int r = atomicAdd(&sdeg[l], 1);
        csr[ebase + sexcl[l] + r] = pr.y;
    }
}

// ---------------- Weight prep: Btg[layer][col][k] bf16, k<128 Wl, k>=128 Wr ----------------

__global__ void prep_w_kernel(const float* __restrict__ Wl, const float* __restrict__ Wr,
                              ushort* __restrict__ Btg) {
    int idx = blockIdx.x * 256 + threadIdx.x;   // 2*128*256 = 65536
    if (idx >= 65536) return;
    int l = idx >> 15;
    int col = (idx >> 8) & 127;
    int k = idx & 255;
    float v = (k < 128) ? Wl[l * H * H + k * H + col] : Wr[l * H * H + (k - 128) * H + col];
    Btg[idx] = f2b(v);
}

// ---------------- Layer 0 (in_dim = 1) ----------------

__global__ void agg0_kernel(const float* __restrict__ x, const int* __restrict__ rs,
                            const int* __restrict__ csr, float* __restrict__ agg0, int n) {
    int i = blockIdx.x * 256 + threadIdx.x;
    if (i >= n) return;
    int a = rs[i], b = rs[i + 1];
    float s = 0.f;
    for (int e = a; e < b; e++) s += x[csr[e]];
    agg0[i] = s / (float)max(b - a, 1);
}

__global__ void expand0_kernel(const float* __restrict__ x, const float* __restrict__ agg0,
                               const float* __restrict__ Wl0, const float* __restrict__ bl0,
                               const float* __restrict__ Wr0, ushort* __restrict__ hout, int n) {
    int idx = blockIdx.x * 256 + threadIdx.x;
    if (idx >= n * H) return;
    int i = idx >> 7, j = idx & (H - 1);
    float v = agg0[i] * Wl0[j] + bl0[j] + x[i] * Wr0[j];
    hout[idx] = f2b(fmaxf(v, 0.f));
}

// ---------------- Aggregate (CSR row-gather mean): 16 lanes/row x short8 ----------------

__global__ void aggregate_kernel(const ushort* __restrict__ hb, const int* __restrict__ rs,
                                 const int* __restrict__ csr, ushort* __restrict__ aggb, int n) {
    int node = blockIdx.x * 4 + (threadIdx.x >> 6);
    int lane = threadIdx.x & 63;
    if (node >= n) return;
    int g = lane >> 4;        // neighbor slot 0..3
    int fl = lane & 15;       // feature block: 8*fl .. 8*fl+7
    int a = rs[node], b = rs[node + 1];
    float s[8] = {0.f, 0.f, 0.f, 0.f, 0.f, 0.f, 0.f, 0.f};
    int e = a;
    for (; e + 8 <= b; e += 8) {
        int n0 = csr[e + g], n1 = csr[e + 4 + g];
        short8 v0 = *(const short8*)(hb + (size_t)n0 * H + 8 * fl);
        short8 v1 = *(const short8*)(hb + (size_t)n1 * H + 8 * fl);
        #pragma unroll
        for (int j = 0; j < 8; j++) s[j] += b2f((ushort)v0[j]) + b2f((ushort)v1[j]);
    }
    for (; e + 4 <= b; e += 4) {
        int n0 = csr[e + g];
        short8 v0 = *(const short8*)(hb + (size_t)n0 * H + 8 * fl);
        #pragma unroll
        for (int j = 0; j < 8; j++) s[j] += b2f((ushort)v0[j]);
    }
    if (e < b && g < (b - e)) {
        int n0 = csr[e + g];
        short8 v0 = *(const short8*)(hb + (size_t)n0 * H + 8 * fl);
        #pragma unroll
        for (int j = 0; j < 8; j++) s[j] += b2f((ushort)v0[j]);
    }
    #pragma unroll
    for (int j = 0; j < 8; j++) {
        s[j] += __shfl_xor(s[j], 16, 64);
        s[j] += __shfl_xor(s[j], 32, 64);
    }
    if (lane < 16) {
        float inv = 1.f / (float)max(b - a, 1);
        short8 o;
        #pragma unroll
        for (int j = 0; j < 8; j++) o[j] = (short)f2b(s[j] * inv);
        *(short8*)(aggb + (size_t)node * H + 8 * fl) = o;
    }
}

// ---------------- Fused dual GEMM, B in registers, transposed MFMA output ----------------
// out = relu([agg|h] @ [Wl;Wr] + b). Wave holds 64-col x 256-k weight panel in registers.
// mfma(Wfrag, Afrag): lane holds 4 consecutive output cols of one row -> 8B stores.
// POOL=true: accumulate per-feature sums instead of storing rows.

template<bool POOL>
__global__ __launch_bounds__(256, 2) void gemm_kernel(
    const ushort* __restrict__ aggb, const ushort* __restrict__ hb,
    const ushort* __restrict__ Btg,   // [128][256] bf16 for this layer
    const float* __restrict__ bias, ushort* __restrict__ out,
    float* __restrict__ partial, int nblk, int n) {
    __shared__ float sums[2][128];
    int tid = threadIdx.x;
    int wave = tid >> 6, lane = tid & 63;
    int l15 = lane & 15, lhi = lane >> 4;
    int colhalf = wave & 1;   // cols 0-63 / 64-127
    int rowsub = wave >> 1;   // rows +0 / +16
    int colbase = colhalf * 64;

    // Weight fragments: bf[c2][s] covers cols colbase+c2*16+l15, k = s*32 + lhi*8 .. +7
    short8 bf[4][8];
    #pragma unroll
    for (int c2 = 0; c2 < 4; c2++) {
        const ushort* wp = Btg + (colbase + c2 * 16 + l15) * 256 + lhi * 8;
        #pragma unroll
        for (int s = 0; s < 8; s++)
            bf[c2][s] = *(const short8*)(wp + s * 32);
    }
    f32x4 bias_v[4];
    #pragma unroll
    for (int c2 = 0; c2 < 4; c2++)
        bias_v[c2] = *(const f32x4*)(bias + colbase + c2 * 16 + lhi * 4);

    f32x4 fs[4];
    #pragma unroll
    for (int c2 = 0; c2 < 4; c2++) fs[c2] = (f32x4){0.f, 0.f, 0.f, 0.f};

    for (int r0 = blockIdx.x * 32; r0 < n; r0 += nblk * 32) {
        int row = r0 + rowsub * 16 + l15;
        int arow = min(row, n - 1);
        short8 af[8];
        #pragma unroll
        for (int s = 0; s < 8; s++)
            af[s] = *(const short8*)((s < 4 ? aggb : hb) + (size_t)arow * H + (s & 3) * 32 + lhi * 8);
        f32x4 acc[4];
        #pragma unroll
        for (int c2 = 0; c2 < 4; c2++) acc[c2] = (f32x4){0.f, 0.f, 0.f, 0.f};
        #pragma unroll
        for (int s = 0; s < 8; s++) {
            #pragma unroll
            for (int c2 = 0; c2 < 4; c2++)
                acc[c2] = __builtin_amdgcn_mfma_f32_16x16x32_bf16(bf[c2][s], af[s], acc[c2], 0, 0, 0);
        }
        if (row < n) {
            if (POOL) {
                #pragma unroll
                for (int c2 = 0; c2 < 4; c2++)
                    #pragma unroll
                    for (int r = 0; r < 4; r++)
                        fs[c2][r] += fmaxf(acc[c2][r] + bias_v[c2][r], 0.f);
            } else {
                #pragma unroll
                for (int c2 = 0; c2 < 4; c2++) {
                    ushort4 o;
                    o.x = f2b(fmaxf(acc[c2][0] + bias_v[c2][0], 0.f));
                    o.y = f2b(fmaxf(acc[c2][1] + bias_v[c2][1], 0.f));
                    o.z = f2b(fmaxf(acc[c2][2] + bias_v[c2][2], 0.f));
                    o.w = f2b(fmaxf(acc[c2][3] + bias_v[c2][3], 0.f));
                    *(ushort4*)(out + (size_t)row * H + colbase + c2 * 16 + lhi * 4) = o;
                }
            }
        }
    }

    if (POOL) {
        // reduce over the 16 row-lanes (l15)
        #pragma unroll
        for (int c2 = 0; c2 < 4; c2++) {
            #pragma unroll
            for (int m = 1; m < 16; m <<= 1) {
                #pragma unroll
                for (int r = 0; r < 4; r++)
                    fs[c2][r] += __shfl_xor(fs[c2][r], m, 64);
            }
        }
        if (l15 == 0) {
            #pragma unroll
            for (int c2 = 0; c2 < 4; c2++)
                #pragma unroll
                for (int r = 0; r < 4; r++)
                    sums[rowsub][colbase + c2 * 16 + lhi * 4 + r] = fs[c2][r];
        }
        __syncthreads();
        if (tid < 128)
            partial[tid * nblk + blockIdx.x] = sums[0][tid] + sums[1][tid];
    }
}

// ---------------- Final pooling reduce: one wave per feature ----------------

__global__ void pool_reduce_kernel(const float* __restrict__ partial, float* __restrict__ pooled,
                                   int nb, float invn) {
    int j = blockIdx.x;      // feature
    int t = threadIdx.x;     // 64 (one wave)
    float s = 0.f;
    for (int b = t; b < nb; b += 64) s += partial[j * nb + b];
    #pragma unroll
    for (int off = 32; off > 0; off >>= 1) s += __shfl_down(s, off, 64);
    if (t == 0) pooled[j] = s * invn;
}

// ---------------- Final MLP ----------------

__global__ void mlp_kernel(const float* __restrict__ pooled,
                           const float* __restrict__ Wv, const float* __restrict__ bv,
                           const float* __restrict__ temp, const float* __restrict__ tt,
                           const float* __restrict__ Wm1, const float* __restrict__ bm1,
                           const float* __restrict__ Wm2, const float* __restrict__ bm2,
                           float* __restrict__ out) {
    __shared__ float feat[66];
    __shared__ float red[2];
    int j = threadIdx.x;  // 128 threads
    if (j < 64) {
        float s = bv[j];
        for (int k = 0; k < H; k++) s += pooled[k] * Wv[k * 64 + j];
        feat[j] = s;
    }
    if (j == 64) feat[64] = temp[0];
    if (j == 65) feat[65] = tt[0];
    __syncthreads();
    float m = bm1[j];
    for (int k = 0; k < 66; k++) m += feat[k] * Wm1[k * H + j];
    m = fmaxf(m, 0.f);
    float p = m * Wm2[j];
    #pragma unroll
    for (int off = 32; off > 0; off >>= 1) p += __shfl_down(p, off, 64);
    if ((j & 63) == 0) red[j >> 6] = p;
    __syncthreads();
    if (j == 0) {
        float x = red[0] + red[1] + bm2[0];
        out[0] = (x > 20.f) ? x : log1pf(expf(x));
    }
}

// ---------------- Launch ----------------

extern "C" void kernel_launch(void* const* d_in, const int* in_sizes, int n_in,
                              void* d_out, int out_size, void* d_ws, size_t ws_size,
                              hipStream_t stream) {
    const float* node_feats = (const float*)d_in[0];
    const int* edge_index = (const int*)d_in[1];
    const float* temp = (const float*)d_in[3];
    const float* tt   = (const float*)d_in[4];
    const float* Wl0 = (const float*)d_in[5];
    const float* bl0 = (const float*)d_in[6];
    const float* Wr0 = (const float*)d_in[7];
    const float* Wl  = (const float*)d_in[8];
    const float* bl  = (const float*)d_in[9];
    const float* Wr  = (const float*)d_in[10];
    const float* Wv  = (const float*)d_in[11];
    const float* bv  = (const float*)d_in[12];
    const float* Wm1 = (const float*)d_in[13];
    const float* bm1 = (const float*)d_in[14];
    const float* Wm2 = (const float*)d_in[15];
    const float* bm2 = (const float*)d_in[16];

    const int N = in_sizes[0];
    const int E = in_sizes[1] / 2;
    const int* src = edge_index;
    const int* dst = edge_index + E;

    size_t NH = (size_t)N * H;
    ushort* hA   = (ushort*)d_ws;            // N*H bf16
    ushort* hB   = hA + NH;                  // N*H bf16
    ushort* aggb = hB + NH;                  // N*H bf16
    ushort* Btg  = aggb + NH;                // 2*128*256 bf16
    float* agg0  = (float*)(Btg + 65536);    // N f32
    int2* grouped = (int2*)(agg0 + N);       // E pairs
    int* csr     = (int*)(grouped + E);      // E
    int* rs      = csr + E;                  // N+1
    int* bucketCount = rs + (N + 1);         // 256
    int* bucketBase  = bucketCount + 256;    // 257
    int* blockBase   = bucketBase + 257;     // NBLK*256
    int NBLK = (E + CHUNK - 1) / CHUNK;
    float* partial = (float*)(blockBase + NBLK * 256);  // H*GEMM_GRID (transposed)
    float* pooled  = partial + (size_t)H * GEMM_GRID;   // H

    int NB = (N + BKT_NODES - 1) / BKT_NODES;

    // CSR build (bucketed)
    hipMemsetAsync(bucketCount, 0, 256 * sizeof(int), stream);
    bucket_hist_kernel<<<NBLK, 256, 0, stream>>>(dst, E, bucketCount, blockBase);
    bucket_scan_kernel<<<1, 64, 0, stream>>>(bucketCount, bucketBase, rs, N, E);
    bucket_scatter_kernel<<<NBLK, 256, 0, stream>>>(src, dst, E, bucketBase, blockBase, grouped);
    bucket_csr_kernel<<<NB, 256, 0, stream>>>(grouped, bucketBase, rs, csr, N);

    // Weights -> bf16 transposed [layer][col][k]
    prep_w_kernel<<<256, 256, 0, stream>>>(Wl, Wr, Btg);

    // Layer 0 scalar part -> hA
    agg0_kernel<<<(N + 255) / 256, 256, 0, stream>>>(node_feats, rs, csr, agg0, N);
    expand0_kernel<<<((size_t)N * H + 255) / 256, 256, 0, stream>>>(node_feats, agg0, Wl0, bl0, Wr0, hA, N);

    // Layer 1: row-gather aggregate on hA -> gemm -> hB
    aggregate_kernel<<<(N + 3) / 4, 256, 0, stream>>>(hA, rs, csr, aggb, N);
    gemm_kernel<false><<<GEMM_GRID, 256, 0, stream>>>(aggb, hA, Btg, bl, hB, nullptr, GEMM_GRID, N);

    // Layer 2: aggregate -> gemm (fused pooling, no h store)
    aggregate_kernel<<<(N + 3) / 4, 256, 0, stream>>>(hB, rs, csr, aggb, N);
    gemm_kernel<true><<<GEMM_GRID, 256, 0, stream>>>(aggb, hB, Btg + 32768, bl + H, nullptr, partial, GEMM_GRID, N);

    // Final pooling reduce + MLP
    pool_reduce_kernel<<<H, 64, 0, stream>>>(partial, pooled, GEMM_GRID, 1.0f / (float)N);
    mlp_kernel<<<1, H, 0, stream>>>(pooled, Wv, bv, temp, tt, Wm1, bm1, Wm2, bm2, (float*)d_out);
}

// Round 8
// 259.387 us; speedup vs baseline: 5.9643x; 1.0725x over previous
//
#include <hip/hip_runtime.h>
#include <hip/hip_bf16.h>
#include <math.h>

#define H 128
#define BKT_SHIFT 9
#define BKT_NODES 512
#define CHUNK 2048   // edges per block in phase A/B
#define GEMM_GRID 512
#define FP8_SCALE 64.0f
#define FP8_INV (1.0f / 64.0f)

typedef __attribute__((ext_vector_type(8))) short short8;
typedef __attribute__((ext_vector_type(4))) float f32x4;
typedef __attribute__((ext_vector_type(2))) float f32x2;

static __device__ __forceinline__ ushort f2b(float v) {
    union { float f; unsigned u; } x; x.f = v;
    unsigned r = x.u + 0x7fffu + ((x.u >> 16) & 1u);
    return (ushort)(r >> 16);
}
static __device__ __forceinline__ float b2f(ushort b) {
    union { unsigned u; float f; } x; x.u = ((unsigned)b) << 16;
    return x.f;
}

// ---------------- Bucketed CSR build ----------------

__global__ void bucket_hist_kernel(const int* __restrict__ dst, int e,
                                   int* __restrict__ bucketCount, int* __restrict__ blockBase) {
    __shared__ int hist[256];
    int t = threadIdx.x;
    hist[t] = 0;
    __syncthreads();
    int base = blockIdx.x * CHUNK;
    #pragma unroll
    for (int k = 0; k < CHUNK / 256; k++) {
        int i = base + k * 256 + t;
        if (i < e) atomicAdd(&hist[dst[i] >> BKT_SHIFT], 1);
    }
    __syncthreads();
    blockBase[blockIdx.x * 256 + t] = atomicAdd(&bucketCount[t], hist[t]);
}

__global__ void bucket_scan_kernel(const int* __restrict__ bucketCount, int* __restrict__ bucketBase,
                                   int* __restrict__ rs, int n, int e) {
    if (threadIdx.x == 0 && blockIdx.x == 0) {
        int acc = 0;
        for (int i = 0; i < 256; i++) { bucketBase[i] = acc; acc += bucketCount[i]; }
        bucketBase[256] = acc;
        rs[n] = e;
    }
}

__global__ void bucket_scatter_kernel(const int* __restrict__ src, const int* __restrict__ dst, int e,
                                      const int* __restrict__ bucketBase, const int* __restrict__ blockBase,
                                      int2* __restrict__ grouped) {
    __shared__ int cur[256];
    int t = threadIdx.x;
    cur[t] = bucketBase[t] + blockBase[blockIdx.x * 256 + t];
    __syncthreads();
    int base = blockIdx.x * CHUNK;
    #pragma unroll
    for (int k = 0; k < CHUNK / 256; k++) {
        int i = base + k * 256 + t;
        if (i < e) {
            int d = dst[i];
            int pos = atomicAdd(&cur[d >> BKT_SHIFT], 1);
            int2 p; p.x = d; p.y = src[i];
            grouped[pos] = p;
        }
    }
}

__global__ void bucket_csr_kernel(const int2* __restrict__ grouped, const int* __restrict__ bucketBase,
                                  int* __restrict__ rs, int* __restrict__ csr, int n) {
    __shared__ int sdeg[BKT_NODES];
    __shared__ int sexcl[BKT_NODES];
    __shared__ int wsum[4];
    int b = blockIdx.x;
    int t = threadIdx.x;
    int nodeBase = b << BKT_SHIFT;
    int ebase = bucketBase[b], eend = bucketBase[b + 1];
    sdeg[t] = 0; sdeg[t + 256] = 0;
    __syncthreads();
    for (int e = ebase + t; e < eend; e += 256)
        atomicAdd(&sdeg[grouped[e].x - nodeBase], 1);
    __syncthreads();
    int lane = t & 63, wid = t >> 6;
    int v0 = sdeg[2 * t], v1 = sdeg[2 * t + 1];
    int p = v0 + v1;
    int x = p;
    #pragma unroll
    for (int off = 1; off < 64; off <<= 1) {
        int y = __shfl_up(x, off, 64);
        if (lane >= off) x += y;
    }
    if (lane == 63) wsum[wid] = x;
    __syncthreads();
    if (t == 0) {
        int acc = 0;
        #pragma unroll
        for (int w = 0; w < 4; w++) { int tmp = wsum[w]; wsum[w] = acc; acc += tmp; }
    }
    __syncthreads();
    int basep = wsum[wid] + x - p;
    sexcl[2 * t] = basep;
    sexcl[2 * t + 1] = basep + v0;
    int nodes = min(BKT_NODES, n - nodeBase);
    for (int i = t; i < nodes; i += 256) rs[nodeBase + i] = ebase + sexcl[i];
    sdeg[t] = 0; sdeg[t + 256] = 0;
    __syncthreads();
    for (int e = ebase + t; e < eend; e += 256) {
        int2 pr = grouped[e];
        int l = pr.x - nodeBase;
        int r = atomicAdd(&sdeg[l], 1);
        csr[ebase + sexcl[l] + r] = pr.y;
    }
}

// ---------------- Weight prep: Btg[layer][col][k] bf16, k<128 Wl, k>=128 Wr ----------------

__global__ void prep_w_kernel(const float* __restrict__ Wl, const float* __restrict__ Wr,
                              ushort* __restrict__ Btg) {
    int idx = blockIdx.x * 256 + threadIdx.x;   // 2*128*256 = 65536
    if (idx >= 65536) return;
    int l = idx >> 15;
    int col = (idx >> 8) & 127;
    int k = idx & 255;
    float v = (k < 128) ? Wl[l * H * H + k * H + col] : Wr[l * H * H + (k - 128) * H + col];
    Btg[idx] = f2b(v);
}

// ---------------- Layer 0 (in_dim = 1) ----------------

__global__ void agg0_kernel(const float* __restrict__ x, const int* __restrict__ rs,
                            const int* __restrict__ csr, float* __restrict__ agg0, int n) {
    int i = blockIdx.x * 256 + threadIdx.x;
    if (i >= n) return;
    int a = rs[i], b = rs[i + 1];
    float s = 0.f;
    for (int e = a; e < b; e++) s += x[csr[e]];
    agg0[i] = s / (float)max(b - a, 1);
}

// each thread: 2 features -> bf16 pair + fp8 pair (scaled)
__global__ void expand0_kernel(const float* __restrict__ x, const float* __restrict__ agg0,
                               const float* __restrict__ Wl0, const float* __restrict__ bl0,
                               const float* __restrict__ Wr0, ushort* __restrict__ hout,
                               ushort* __restrict__ h8, int n) {
    int idx = blockIdx.x * 256 + threadIdx.x;   // over N*64
    if (idx >= n * 64) return;
    int i = idx >> 6, j = (idx & 63) * 2;
    float gi = agg0[i], xi = x[i];
    float v0 = fmaxf(gi * Wl0[j] + bl0[j] + xi * Wr0[j], 0.f);
    float v1 = fmaxf(gi * Wl0[j + 1] + bl0[j + 1] + xi * Wr0[j + 1], 0.f);
    ushort2 o; o.x = f2b(v0); o.y = f2b(v1);
    *(ushort2*)(hout + (size_t)i * H + j) = o;
    int p = __builtin_amdgcn_cvt_pk_fp8_f32(v0 * FP8_SCALE, v1 * FP8_SCALE, 0, false);
    h8[(size_t)i * 64 + (idx & 63)] = (ushort)p;
}

// ---------------- Aggregate from fp8 shadow: 2 nodes/wave, 4 slots x 8 lanes x 16B ----------------

__global__ void aggregate8_kernel(const unsigned char* __restrict__ h8, const int* __restrict__ rs,
                                  const int* __restrict__ csr, ushort* __restrict__ aggb, int n) {
    int tid = threadIdx.x;
    int w = (tid >> 5) & 1;          // node within wave
    int node = blockIdx.x * 8 + (tid >> 6) * 2 + w;
    if (node >= n) return;
    int sl = (tid >> 3) & 3;         // neighbor slot 0..3
    int fl = tid & 7;                // 16-feature block
    int a = rs[node], b = rs[node + 1];
    f32x2 s[8];
    #pragma unroll
    for (int j = 0; j < 8; j++) s[j] = (f32x2){0.f, 0.f};

    int e = a;
    for (; e + 8 <= b; e += 8) {
        int n0 = csr[e + sl], n1 = csr[e + 4 + sl];
        uint4 u0 = *(const uint4*)(h8 + (size_t)n0 * 128 + 16 * fl);
        uint4 u1 = *(const uint4*)(h8 + (size_t)n1 * 128 + 16 * fl);
        unsigned dw[8] = {u0.x, u0.y, u0.z, u0.w, u1.x, u1.y, u1.z, u1.w};
        #pragma unroll
        for (int d = 0; d < 8; d++) {
            f32x2 lo = __builtin_amdgcn_cvt_pk_f32_fp8(dw[d], false);
            f32x2 hi = __builtin_amdgcn_cvt_pk_f32_fp8(dw[d], true);
            s[(d & 3) * 2] += lo;
            s[(d & 3) * 2 + 1] += hi;
        }
    }
    for (; e + 4 <= b; e += 4) {
        int n0 = csr[e + sl];
        uint4 u0 = *(const uint4*)(h8 + (size_t)n0 * 128 + 16 * fl);
        unsigned dw[4] = {u0.x, u0.y, u0.z, u0.w};
        #pragma unroll
        for (int d = 0; d < 4; d++) {
            f32x2 lo = __builtin_amdgcn_cvt_pk_f32_fp8(dw[d], false);
            f32x2 hi = __builtin_amdgcn_cvt_pk_f32_fp8(dw[d], true);
            s[d * 2] += lo;
            s[d * 2 + 1] += hi;
        }
    }
    if (e < b && sl < (b - e)) {
        int n0 = csr[e + sl];
        uint4 u0 = *(const uint4*)(h8 + (size_t)n0 * 128 + 16 * fl);
        unsigned dw[4] = {u0.x, u0.y, u0.z, u0.w};
        #pragma unroll
        for (int d = 0; d < 4; d++) {
            f32x2 lo = __builtin_amdgcn_cvt_pk_f32_fp8(dw[d], false);
            f32x2 hi = __builtin_amdgcn_cvt_pk_f32_fp8(dw[d], true);
            s[d * 2] += lo;
            s[d * 2 + 1] += hi;
        }
    }
    // reduce across the 4 slots (xor 8, 16 stay within the 32-lane node group)
    #pragma unroll
    for (int j = 0; j < 8; j++) {
        s[j].x += __shfl_xor(s[j].x, 8, 64);
        s[j].y += __shfl_xor(s[j].y, 8, 64);
        s[j].x += __shfl_xor(s[j].x, 16, 64);
        s[j].y += __shfl_xor(s[j].y, 16, 64);
    }
    if (sl == 0) {
        float inv = FP8_INV / (float)max(b - a, 1);
        short8 o0, o1;
        #pragma unroll
        for (int j = 0; j < 4; j++) {
            o0[2 * j]     = (short)f2b(s[j].x * inv);
            o0[2 * j + 1] = (short)f2b(s[j].y * inv);
            o1[2 * j]     = (short)f2b(s[j + 4].x * inv);
            o1[2 * j + 1] = (short)f2b(s[j + 4].y * inv);
        }
        ushort* dstp = aggb + (size_t)node * H + 16 * fl;
        *(short8*)dstp = o0;
        *(short8*)(dstp + 8) = o1;
    }
}

// ---------------- Fused dual GEMM, B in registers, transposed MFMA output ----------------
// POOL=false: store bf16 rows + fp8 shadow. POOL=true: accumulate feature sums.

template<bool POOL>
__global__ __launch_bounds__(256, 2) void gemm_kernel(
    const ushort* __restrict__ aggb, const ushort* __restrict__ hb,
    const ushort* __restrict__ Btg,   // [128][256] bf16 for this layer
    const float* __restrict__ bias, ushort* __restrict__ out,
    unsigned char* __restrict__ out8,
    float* __restrict__ partial, int nblk, int n) {
    __shared__ float sums[2][128];
    int tid = threadIdx.x;
    int wave = tid >> 6, lane = tid & 63;
    int l15 = lane & 15, lhi = lane >> 4;
    int colhalf = wave & 1;
    int rowsub = wave >> 1;
    int colbase = colhalf * 64;

    short8 bf[4][8];
    #pragma unroll
    for (int c2 = 0; c2 < 4; c2++) {
        const ushort* wp = Btg + (colbase + c2 * 16 + l15) * 256 + lhi * 8;
        #pragma unroll
        for (int s = 0; s < 8; s++)
            bf[c2][s] = *(const short8*)(wp + s * 32);
    }
    f32x4 bias_v[4];
    #pragma unroll
    for (int c2 = 0; c2 < 4; c2++)
        bias_v[c2] = *(const f32x4*)(bias + colbase + c2 * 16 + lhi * 4);

    f32x4 fs[4];
    #pragma unroll
    for (int c2 = 0; c2 < 4; c2++) fs[c2] = (f32x4){0.f, 0.f, 0.f, 0.f};

    for (int r0 = blockIdx.x * 32; r0 < n; r0 += nblk * 32) {
        int row = r0 + rowsub * 16 + l15;
        int arow = min(row, n - 1);
        short8 af[8];
        #pragma unroll
        for (int s = 0; s < 8; s++)
            af[s] = *(const short8*)((s < 4 ? aggb : hb) + (size_t)arow * H + (s & 3) * 32 + lhi * 8);
        f32x4 acc[4];
        #pragma unroll
        for (int c2 = 0; c2 < 4; c2++) acc[c2] = (f32x4){0.f, 0.f, 0.f, 0.f};
        #pragma unroll
        for (int s = 0; s < 8; s++) {
            #pragma unroll
            for (int c2 = 0; c2 < 4; c2++)
                acc[c2] = __builtin_amdgcn_mfma_f32_16x16x32_bf16(bf[c2][s], af[s], acc[c2], 0, 0, 0);
        }
        if (row < n) {
            if (POOL) {
                #pragma unroll
                for (int c2 = 0; c2 < 4; c2++)
                    #pragma unroll
                    for (int r = 0; r < 4; r++)
                        fs[c2][r] += fmaxf(acc[c2][r] + bias_v[c2][r], 0.f);
            } else {
                #pragma unroll
                for (int c2 = 0; c2 < 4; c2++) {
                    float v0 = fmaxf(acc[c2][0] + bias_v[c2][0], 0.f);
                    float v1 = fmaxf(acc[c2][1] + bias_v[c2][1], 0.f);
                    float v2 = fmaxf(acc[c2][2] + bias_v[c2][2], 0.f);
                    float v3 = fmaxf(acc[c2][3] + bias_v[c2][3], 0.f);
                    ushort4 o;
                    o.x = f2b(v0); o.y = f2b(v1); o.z = f2b(v2); o.w = f2b(v3);
                    *(ushort4*)(out + (size_t)row * H + colbase + c2 * 16 + lhi * 4) = o;
                    int p = __builtin_amdgcn_cvt_pk_fp8_f32(v0 * FP8_SCALE, v1 * FP8_SCALE, 0, false);
                    p = __builtin_amdgcn_cvt_pk_fp8_f32(v2 * FP8_SCALE, v3 * FP8_SCALE, p, true);
                    *(unsigned int*)(out8 + (size_t)row * 128 + colbase + c2 * 16 + lhi * 4) = (unsigned)p;
                }
            }
        }
    }

    if (POOL) {
        #pragma unroll
        for (int c2 = 0; c2 < 4; c2++) {
            #pragma unroll
            for (int m = 1; m < 16; m <<= 1) {
                #pragma unroll
                for (int r = 0; r < 4; r++)
                    fs[c2][r] += __shfl_xor(fs[c2][r], m, 64);
            }
        }
        if (l15 == 0) {
            #pragma unroll
            for (int c2 = 0; c2 < 4; c2++)
                #pragma unroll
                for (int r = 0; r < 4; r++)
                    sums[rowsub][colbase + c2 * 16 + lhi * 4 + r] = fs[c2][r];
        }
        __syncthreads();
        if (tid < 128)
            partial[tid * nblk + blockIdx.x] = sums[0][tid] + sums[1][tid];
    }
}

// ---------------- Final pooling reduce: one wave per feature ----------------

__global__ void pool_reduce_kernel(const float* __restrict__ partial, float* __restrict__ pooled,
                                   int nb, float invn) {
    int j = blockIdx.x;
    int t = threadIdx.x;     // 64
    float s = 0.f;
    for (int b = t; b < nb; b += 64) s += partial[j * nb + b];
    #pragma unroll
    for (int off = 32; off > 0; off >>= 1) s += __shfl_down(s, off, 64);
    if (t == 0) pooled[j] = s * invn;
}

// ---------------- Final MLP ----------------

__global__ void mlp_kernel(const float* __restrict__ pooled,
                           const float* __restrict__ Wv, const float* __restrict__ bv,
                           const float* __restrict__ temp, const float* __restrict__ tt,
                           const float* __restrict__ Wm1, const float* __restrict__ bm1,
                           const float* __restrict__ Wm2, const float* __restrict__ bm2,
                           float* __restrict__ out) {
    __shared__ float feat[66];
    __shared__ float red[2];
    int j = threadIdx.x;  // 128 threads
    if (j < 64) {
        float s = bv[j];
        for (int k = 0; k < H; k++) s += pooled[k] * Wv[k * 64 + j];
        feat[j] = s;
    }
    if (j == 64) feat[64] = temp[0];
    if (j == 65) feat[65] = tt[0];
    __syncthreads();
    float m = bm1[j];
    for (int k = 0; k < 66; k++) m += feat[k] * Wm1[k * H + j];
    m = fmaxf(m, 0.f);
    float p = m * Wm2[j];
    #pragma unroll
    for (int off = 32; off > 0; off >>= 1) p += __shfl_down(p, off, 64);
    if ((j & 63) == 0) red[j >> 6] = p;
    __syncthreads();
    if (j == 0) {
        float x = red[0] + red[1] + bm2[0];
        out[0] = (x > 20.f) ? x : log1pf(expf(x));
    }
}

// ---------------- Launch ----------------

extern "C" void kernel_launch(void* const* d_in, const int* in_sizes, int n_in,
                              void* d_out, int out_size, void* d_ws, size_t ws_size,
                              hipStream_t stream) {
    const float* node_feats = (const float*)d_in[0];
    const int* edge_index = (const int*)d_in[1];
    const float* temp = (const float*)d_in[3];
    const float* tt   = (const float*)d_in[4];
    const float* Wl0 = (const float*)d_in[5];
    const float* bl0 = (const float*)d_in[6];
    const float* Wr0 = (const float*)d_in[7];
    const float* Wl  = (const float*)d_in[8];
    const float* bl  = (const float*)d_in[9];
    const float* Wr  = (const float*)d_in[10];
    const float* Wv  = (const float*)d_in[11];
    const float* bv  = (const float*)d_in[12];
    const float* Wm1 = (const float*)d_in[13];
    const float* bm1 = (const float*)d_in[14];
    const float* Wm2 = (const float*)d_in[15];
    const float* bm2 = (const float*)d_in[16];

    const int N = in_sizes[0];
    const int E = in_sizes[1] / 2;
    const int* src = edge_index;
    const int* dst = edge_index + E;

    size_t NH = (size_t)N * H;
    ushort* hA   = (ushort*)d_ws;            // N*H bf16
    ushort* hB   = hA + NH;                  // N*H bf16
    ushort* aggb = hB + NH;                  // N*H bf16
    ushort* Btg  = aggb + NH;                // 2*128*256 bf16
    float* agg0  = (float*)(Btg + 65536);    // N f32
    int2* grouped = (int2*)(agg0 + N);       // E pairs (dead after CSR build)
    int* csr     = (int*)(grouped + E);      // E
    int* rs      = csr + E;                  // N+1
    int* bucketCount = rs + (N + 1);         // 256
    int* bucketBase  = bucketCount + 256;    // 257
    int* blockBase   = bucketBase + 257;     // NBLK*256
    int NBLK = (E + CHUNK - 1) / CHUNK;
    float* partial = (float*)(blockBase + NBLK * 256);  // H*GEMM_GRID
    float* pooled  = partial + (size_t)H * GEMM_GRID;   // H
    unsigned char* hB8 = (unsigned char*)(pooled + H);  // N*128 fp8
    unsigned char* hA8 = (unsigned char*)grouped;       // aliases dead 'grouped'

    int NB = (N + BKT_NODES - 1) / BKT_NODES;

    // CSR build (bucketed)
    hipMemsetAsync(bucketCount, 0, 256 * sizeof(int), stream);
    bucket_hist_kernel<<<NBLK, 256, 0, stream>>>(dst, E, bucketCount, blockBase);
    bucket_scan_kernel<<<1, 64, 0, stream>>>(bucketCount, bucketBase, rs, N, E);
    bucket_scatter_kernel<<<NBLK, 256, 0, stream>>>(src, dst, E, bucketBase, blockBase, grouped);
    bucket_csr_kernel<<<NB, 256, 0, stream>>>(grouped, bucketBase, rs, csr, N);

    // Weights -> bf16 transposed [layer][col][k]
    prep_w_kernel<<<256, 256, 0, stream>>>(Wl, Wr, Btg);

    // Layer 0 scalar part -> hA (bf16) + hA8 (fp8, after grouped is dead)
    agg0_kernel<<<(N + 255) / 256, 256, 0, stream>>>(node_feats, rs, csr, agg0, N);
    expand0_kernel<<<((size_t)N * 64 + 255) / 256, 256, 0, stream>>>(
        node_feats, agg0, Wl0, bl0, Wr0, hA, (ushort*)hA8, N);

    // Layer 1: fp8 gather-mean on hA8 -> gemm -> hB (+ hB8 shadow)
    aggregate8_kernel<<<(N + 7) / 8, 256, 0, stream>>>(hA8, rs, csr, aggb, N);
    gemm_kernel<false><<<GEMM_GRID, 256, 0, stream>>>(aggb, hA, Btg, bl, hB, hB8, nullptr, GEMM_GRID, N);

    // Layer 2: fp8 gather-mean on hB8 -> gemm (fused pooling)
    aggregate8_kernel<<<(N + 7) / 8, 256, 0, stream>>>(hB8, rs, csr, aggb, N);
    gemm_kernel<true><<<GEMM_GRID, 256, 0, stream>>>(aggb, hB, Btg + 32768, bl + H, nullptr, nullptr, partial, GEMM_GRID, N);

    // Final pooling reduce + MLP
    pool_reduce_kernel<<<H, 64, 0, stream>>>(partial, pooled, GEMM_GRID, 1.0f / (float)N);
    mlp_kernel<<<1, H, 0, stream>>>(pooled, Wv, bv, temp, tt, Wm1, bm1, Wm2, bm2, (float*)d_out);
}